// Round 2
// baseline (968.799 us; speedup 1.0000x reference)
//
#include <hip/hip_runtime.h>
#include <hip/hip_bf16.h>
#include <cmath>

#define DEVFN __device__ __forceinline__

typedef __attribute__((ext_vector_type(8))) short short8;
typedef __attribute__((ext_vector_type(4))) float f32x4;

constexpr int C_DIM   = 1024;
constexpr int E_NUM   = 8;
constexpr int DFF_DIM = 4096;
constexpr int NTOK    = 8192;       // B*T
constexpr int TILE    = 128;
constexpr int MAXROWS = NTOK * 2 + E_NUM * TILE;  // 17408 (worst-case padded)

DEVFN unsigned short f2bf(float f) {
    __hip_bfloat16 h = __float2bfloat16(f);
    return __builtin_bit_cast(unsigned short, h);
}
DEVFN float bf2f(unsigned short u) {
    return __bfloat162float(__builtin_bit_cast(__hip_bfloat16, u));
}
DEVFN void gload_lds16(const void* g, void* lds) {
    __builtin_amdgcn_global_load_lds(
        (const __attribute__((address_space(1))) unsigned int*)g,
        (__attribute__((address_space(3))) unsigned int*)lds, 16, 0, 0);
}

// meta layout (ints): [0..7] counts, [8..15] cursor, [16..24] offs (offs[8]=padTotal)

__global__ void init_kernel(int* meta, int* rowtok, float* rowwt) {
    int gid = blockIdx.x * 256 + threadIdx.x;
    if (gid < 64) meta[gid] = 0;
    if (gid < MAXROWS) { rowtok[gid] = 0; rowwt[gid] = 0.f; }
}

// One wave per token: fp64-accumulated gate/noise logits -> exact top-2 + weights.
__global__ void router_kernel(const float* __restrict__ x, const float* __restrict__ noise,
                              const float* __restrict__ wg, const float* __restrict__ bg,
                              const float* __restrict__ wn, const float* __restrict__ bn,
                              int* meta, int2* tok_e, float2* tok_w) {
    int wv = threadIdx.x >> 6, lane = threadIdx.x & 63;
    int t = blockIdx.x * 4 + wv;
    const float* xr = x + (size_t)t * C_DIM;
    double acc[16];
#pragma unroll
    for (int i = 0; i < 16; i++) acc[i] = 0.0;
    for (int i = 0; i < C_DIM / 64; i++) {
        int c = lane + i * 64;
        double xv = (double)xr[c];
        const float* g = wg + c * E_NUM;
        const float* nz = wn + c * E_NUM;
#pragma unroll
        for (int e = 0; e < 8; e++) {
            acc[e]     += xv * (double)g[e];
            acc[8 + e] += xv * (double)nz[e];
        }
    }
#pragma unroll
    for (int s = 32; s >= 1; s >>= 1) {
#pragma unroll
        for (int j = 0; j < 16; j++) acc[j] += __shfl_xor(acc[j], s, 64);
    }
    if (lane == 0) {
        double logit[8];
#pragma unroll
        for (int e = 0; e < 8; e++) {
            double cl = acc[e] + (double)bg[e];
            double nl = acc[8 + e] + (double)bn[e];
            double sp = (nl > 30.0) ? nl : log1p(exp(nl));
            logit[e] = cl + (double)noise[(size_t)t * 8 + e] * sp;
        }
        int i1 = -1, i2 = -1;
        double v1 = -1e300, v2 = -1e300;
#pragma unroll
        for (int e = 0; e < 8; e++) {
            double v = logit[e];
            if (v > v1) { v2 = v1; i2 = i1; v1 = v; i1 = e; }
            else if (v > v2) { v2 = v; i2 = e; }
        }
        double d = exp(v2 - v1);
        tok_e[t] = make_int2(i1, i2);
        tok_w[t] = make_float2((float)(1.0 / (1.0 + d)), (float)(d / (1.0 + d)));
        atomicAdd(&meta[i1], 1);
        atomicAdd(&meta[i2], 1);
    }
}

__global__ void offsets_kernel(int* meta) {
    if (threadIdx.x == 0 && blockIdx.x == 0) {
        int off = 0;
        for (int e = 0; e < 8; e++) {
            meta[16 + e] = off;
            off += (meta[e] + TILE - 1) / TILE * TILE;
            meta[8 + e] = 0;  // cursor
        }
        meta[24] = off;  // padTotal
    }
}

__global__ void assign_kernel(int* meta, const int2* tok_e, const float2* tok_w,
                              int2* tok_pos, int* rowtok, float* rowwt) {
    int t = blockIdx.x * 256 + threadIdx.x;
    int2 e = tok_e[t];
    float2 w = tok_w[t];
    int p0 = meta[16 + e.x] + atomicAdd(&meta[8 + e.x], 1);
    int p1 = meta[16 + e.y] + atomicAdd(&meta[8 + e.y], 1);
    tok_pos[t] = make_int2(p0, p1);
    rowtok[p0] = t; rowwt[p0] = w.x;
    rowtok[p1] = t; rowwt[p1] = w.y;
}

// Gather token rows into packed order, fp32 -> bf16.
__global__ void gather_x_kernel(const float* __restrict__ x, const int* __restrict__ rowtok,
                                unsigned short* __restrict__ Xg) {
    int p = blockIdx.x;
    int tok = rowtok[p];
    const float4* src = (const float4*)(x + (size_t)tok * C_DIM);
    ushort4* dst = (ushort4*)(Xg + (size_t)p * C_DIM);
    int i = threadIdx.x;  // 256 threads x 4 elems = 1024
    float4 v = src[i];
    ushort4 o;
    o.x = f2bf(v.x); o.y = f2bf(v.y); o.z = f2bf(v.z); o.w = f2bf(v.w);
    dst[i] = o;
}

// [E][R][S] fp32 -> [E][S][R] bf16 (gives B in [N][K] layout for contiguous-K frags)
__global__ void transpose_bf16_kernel(const float* __restrict__ in, unsigned short* __restrict__ out,
                                      int R, int S) {
    __shared__ float tile[32][33];
    const float* ine = in + (size_t)blockIdx.z * R * S;
    unsigned short* oute = out + (size_t)blockIdx.z * R * S;
    int s0 = blockIdx.x * 32, r0 = blockIdx.y * 32;
    int tx = threadIdx.x & 31, ty = threadIdx.x >> 5;  // ty in [0,8)
#pragma unroll
    for (int j = 0; j < 32; j += 8)
        tile[ty + j][tx] = ine[(size_t)(r0 + ty + j) * S + s0 + tx];
    __syncthreads();
#pragma unroll
    for (int j = 0; j < 32; j += 8)
        oute[(size_t)(s0 + ty + j) * R + r0 + tx] = f2bf(tile[tx][ty + j]);
}

// 128x128 tile GEMM, 4 waves (2x2 of 64x64), BK=64 as two 32-halves.
// A: [rows][KDIM] bf16 (packed). Bt: [E][NDIM][KDIM] bf16. LDS dest linear for
// global_load_lds; bank-conflict fix = inverse-XOR-swizzled SOURCE + swizzled read.
// MODE 1: Out = bf16(relu(acc + bias))            (writes H, bf16)
// MODE 2: Out = fp32((acc + bias) * rowwt[row])   (writes contrib, fp32, direct)
template <int KDIM, int NDIM, int MODE>
__global__ __launch_bounds__(256) void gemm_kernel(
    const unsigned short* __restrict__ A, const unsigned short* __restrict__ Bt,
    const float* __restrict__ bias, const float* __restrict__ rowwt,
    void* __restrict__ OutV, const int* __restrict__ meta) {
    int rowBase = blockIdx.x * TILE;
    int padTotal = meta[24];
    if (rowBase >= padTotal) return;
    int e = 0;
#pragma unroll
    for (int i = 1; i < 8; i++)
        if (rowBase >= meta[16 + i]) e = i;
    int colBase = blockIdx.y * TILE;

    __shared__ unsigned short lds[16384];  // 32KB: A halves [0,8192), B halves [8192,16384)
    unsigned short* Al = lds;
    unsigned short* Bl = lds + 8192;

    int tid = threadIdx.x;
    int wv = tid >> 6, lane = tid & 63;
    int wr = wv >> 1, wc = wv & 1;

    const unsigned short* Ab = A + (size_t)rowBase * KDIM;
    const unsigned short* Bb = Bt + (size_t)e * NDIM * KDIM + (size_t)colBase * KDIM;

    f32x4 acc[4][4];
#pragma unroll
    for (int m = 0; m < 4; m++)
#pragma unroll
        for (int n = 0; n < 4; n++) acc[m][n] = f32x4{0.f, 0.f, 0.f, 0.f};

    // Precompute swizzled frag byte-offsets (same every K-step; LDS single-buffered)
    int aoff[4], boff[4];
#pragma unroll
    for (int m = 0; m < 4; m++) {
        int r = wr * 64 + m * 16 + (lane & 15);
        aoff[m] = r * 64 + ((((lane >> 4) ^ ((r >> 1) & 3))) << 4);
        int rb = wc * 64 + m * 16 + (lane & 15);
        boff[m] = rb * 64 + ((((lane >> 4) ^ ((rb >> 1) & 3))) << 4);
    }

    const int kSteps = KDIM / 64;
    for (int ks = 0; ks < kSteps; ++ks) {
        int k0 = ks * 64;
        // Stage A and B tiles: 2 halves x [128 rows][32 k] bf16 each (16KB each)
#pragma unroll
        for (int i = 0; i < 4; i++) {
            int ob = i * 4096 + wv * 1024;  // wave-uniform LDS byte base
            int o = ob + lane * 16;
            int kk = o >> 13;
            int rem = o & 8191;
            int r = rem >> 6;
            int cp = (rem >> 4) & 3;
            int cc = cp ^ ((r >> 1) & 3);  // inverse swizzle on SOURCE
            gload_lds16(Ab + (size_t)r * KDIM + (k0 + kk * 32 + cc * 8), (char*)Al + ob);
            gload_lds16(Bb + (size_t)r * KDIM + (k0 + kk * 32 + cc * 8), (char*)Bl + ob);
        }
        __syncthreads();
#pragma unroll
        for (int kk = 0; kk < 2; kk++) {
            short8 af[4], bfr[4];
#pragma unroll
            for (int m = 0; m < 4; m++)
                af[m] = *(const short8*)((const char*)Al + kk * 8192 + aoff[m]);
#pragma unroll
            for (int n = 0; n < 4; n++)
                bfr[n] = *(const short8*)((const char*)Bl + kk * 8192 + boff[n]);
#pragma unroll
            for (int m = 0; m < 4; m++)
#pragma unroll
                for (int n = 0; n < 4; n++)
                    acc[m][n] = __builtin_amdgcn_mfma_f32_16x16x32_bf16(af[m], bfr[n], acc[m][n], 0, 0, 0);
        }
        __syncthreads();
    }

    // Epilogue.
    float bv[4];
#pragma unroll
    for (int n = 0; n < 4; n++)
        bv[n] = bias[(size_t)e * NDIM + colBase + wc * 64 + n * 16 + (lane & 15)];

    if constexpr (MODE == 1) {
        // relu -> bf16, repack through LDS, coalesced 16B stores.
#pragma unroll
        for (int m = 0; m < 4; m++) {
#pragma unroll
            for (int n = 0; n < 4; n++) {
#pragma unroll
                for (int j = 0; j < 4; j++) {
                    float v = fmaxf(acc[m][n][j] + bv[n], 0.f);
                    int rr = wr * 64 + m * 16 + (lane >> 4) * 4 + j;
                    int cc = wc * 64 + n * 16 + (lane & 15);
                    lds[rr * TILE + cc] = f2bf(v);
                }
            }
        }
        __syncthreads();
        int row = tid >> 1, half = tid & 1;
        const short8* s = (const short8*)(lds + row * TILE + half * 64);
        short8* dst = (short8*)((unsigned short*)OutV + (size_t)(rowBase + row) * NDIM + colBase + half * 64);
#pragma unroll
        for (int i = 0; i < 8; i++) dst[i] = s[i];  // 8 x 8 shorts = full 64
    } else {
        // weight-scale -> fp32, direct stores (64B per 16-lane group).
        float* Of = (float*)OutV;
#pragma unroll
        for (int m = 0; m < 4; m++) {
            float wt[4];
#pragma unroll
            for (int j = 0; j < 4; j++)
                wt[j] = rowwt[rowBase + wr * 64 + m * 16 + (lane >> 4) * 4 + j];
#pragma unroll
            for (int n = 0; n < 4; n++) {
#pragma unroll
                for (int j = 0; j < 4; j++) {
                    float v = (acc[m][n][j] + bv[n]) * wt[j];
                    int rr = wr * 64 + m * 16 + (lane >> 4) * 4 + j;
                    int cc = wc * 64 + n * 16 + (lane & 15);
                    Of[(size_t)(rowBase + rr) * NDIM + colBase + cc] = v;
                }
            }
        }
    }
}

__global__ void combine_kernel(const float* __restrict__ contrib,
                               const int2* __restrict__ tok_pos, float* __restrict__ out) {
    int t = blockIdx.x;
    int2 p = tok_pos[t];
    const float4* c0 = (const float4*)(contrib + (size_t)p.x * C_DIM);
    const float4* c1 = (const float4*)(contrib + (size_t)p.y * C_DIM);
    float4* o = (float4*)(out + (size_t)t * C_DIM);
    int i = threadIdx.x;  // 256 x 4 = 1024
    float4 a = c0[i], b = c1[i];
    float4 r;
    r.x = a.x + b.x; r.y = a.y + b.y; r.z = a.z + b.z; r.w = a.w + b.w;
    o[i] = r;
}

extern "C" void kernel_launch(void* const* d_in, const int* in_sizes, int n_in,
                              void* d_out, int out_size, void* d_ws, size_t ws_size,
                              hipStream_t stream) {
    (void)in_sizes; (void)n_in; (void)out_size; (void)ws_size;
    const float* x       = (const float*)d_in[0];
    const float* noise   = (const float*)d_in[1];
    const float* w_gate  = (const float*)d_in[2];
    const float* b_gate  = (const float*)d_in[3];
    const float* w_noise = (const float*)d_in[4];
    const float* b_noise = (const float*)d_in[5];
    const float* w1      = (const float*)d_in[6];
    const float* b1      = (const float*)d_in[7];
    const float* w2      = (const float*)d_in[8];
    const float* b2      = (const float*)d_in[9];
    float* out = (float*)d_out;

    char* w = (char*)d_ws;
    size_t off = 0;
    int* meta = (int*)(w + off); off += 256;
    int2* tok_e = (int2*)(w + off); off += (size_t)NTOK * 8;
    float2* tok_w = (float2*)(w + off); off += (size_t)NTOK * 8;
    int2* tok_pos = (int2*)(w + off); off += (size_t)NTOK * 8;
    int* rowtok = (int*)(w + off); off += (size_t)MAXROWS * 4;
    float* rowwt = (float*)(w + off); off += (size_t)MAXROWS * 4;
    unsigned short* Xg = (unsigned short*)(w + off); off += (size_t)MAXROWS * C_DIM * 2;
    unsigned short* H = (unsigned short*)(w + off); off += (size_t)MAXROWS * DFF_DIM * 2;
    unsigned short* w1b = (unsigned short*)(w + off); off += (size_t)E_NUM * DFF_DIM * C_DIM * 2;
    unsigned short* w2b = (unsigned short*)(w + off); off += (size_t)E_NUM * C_DIM * DFF_DIM * 2;
    float* contrib = (float*)(w + off); off += (size_t)MAXROWS * C_DIM * 4;

    init_kernel<<<(MAXROWS + 255) / 256, 256, 0, stream>>>(meta, rowtok, rowwt);
    router_kernel<<<NTOK / 4, 256, 0, stream>>>(x, noise, w_gate, b_gate, w_noise, b_noise,
                                                meta, tok_e, tok_w);
    offsets_kernel<<<1, 64, 0, stream>>>(meta);
    assign_kernel<<<NTOK / 256, 256, 0, stream>>>(meta, tok_e, tok_w, tok_pos, rowtok, rowwt);
    gather_x_kernel<<<MAXROWS, 256, 0, stream>>>(x, rowtok, Xg);
    transpose_bf16_kernel<<<dim3(DFF_DIM / 32, C_DIM / 32, E_NUM), 256, 0, stream>>>(w1, w1b, C_DIM, DFF_DIM);
    transpose_bf16_kernel<<<dim3(C_DIM / 32, DFF_DIM / 32, E_NUM), 256, 0, stream>>>(w2, w2b, DFF_DIM, C_DIM);
    gemm_kernel<C_DIM, DFF_DIM, 1><<<dim3(MAXROWS / TILE, DFF_DIM / TILE), 256, 0, stream>>>(
        Xg, w1b, b1, nullptr, H, meta);
    gemm_kernel<DFF_DIM, C_DIM, 2><<<dim3(MAXROWS / TILE, C_DIM / TILE), 256, 0, stream>>>(
        H, w2b, b2, rowwt, contrib, meta);
    combine_kernel<<<NTOK, 256, 0, stream>>>(contrib, tok_pos, out);
}

// Round 3
// 904.683 us; speedup vs baseline: 1.0709x; 1.0709x over previous
//
#include <hip/hip_runtime.h>
#include <hip/hip_bf16.h>
#include <cmath>

#define DEVFN __device__ __forceinline__

typedef __attribute__((ext_vector_type(8))) short short8;
typedef __attribute__((ext_vector_type(4))) float f32x4;

constexpr int C_DIM   = 1024;
constexpr int E_NUM   = 8;
constexpr int DFF_DIM = 4096;
constexpr int NTOK    = 8192;       // B*T
constexpr int PAD     = 256;        // expert segment alignment
constexpr int MAXROWS = NTOK * 2 + E_NUM * PAD;  // 18432

DEVFN unsigned short f2bf(float f) {
    __hip_bfloat16 h = __float2bfloat16(f);
    return __builtin_bit_cast(unsigned short, h);
}
DEVFN float bf2f(unsigned short u) {
    return __bfloat162float(__builtin_bit_cast(__hip_bfloat16, u));
}
DEVFN void gload_lds16(const void* g, void* lds) {
    __builtin_amdgcn_global_load_lds(
        (const __attribute__((address_space(1))) unsigned int*)g,
        (__attribute__((address_space(3))) unsigned int*)lds, 16, 0, 0);
}

// meta layout (ints): [0..7] counts, [8..15] cursor, [16..24] offs (offs[8]=padTotal)

__global__ void init_kernel(int* meta, int* rowtok, float* rowwt) {
    int gid = blockIdx.x * 256 + threadIdx.x;
    if (gid < 64) meta[gid] = 0;
    if (gid < MAXROWS) { rowtok[gid] = 0; rowwt[gid] = 0.f; }
}

// One wave per token: fp64-accumulated gate/noise logits -> exact top-2 + weights.
__global__ void router_kernel(const float* __restrict__ x, const float* __restrict__ noise,
                              const float* __restrict__ wg, const float* __restrict__ bg,
                              const float* __restrict__ wn, const float* __restrict__ bn,
                              int* meta, int2* tok_e, float2* tok_w) {
    int wv = threadIdx.x >> 6, lane = threadIdx.x & 63;
    int t = blockIdx.x * 4 + wv;
    const float* xr = x + (size_t)t * C_DIM;
    double acc[16];
#pragma unroll
    for (int i = 0; i < 16; i++) acc[i] = 0.0;
    for (int i = 0; i < C_DIM / 64; i++) {
        int c = lane + i * 64;
        double xv = (double)xr[c];
        const float* g = wg + c * E_NUM;
        const float* nz = wn + c * E_NUM;
#pragma unroll
        for (int e = 0; e < 8; e++) {
            acc[e]     += xv * (double)g[e];
            acc[8 + e] += xv * (double)nz[e];
        }
    }
#pragma unroll
    for (int s = 32; s >= 1; s >>= 1) {
#pragma unroll
        for (int j = 0; j < 16; j++) acc[j] += __shfl_xor(acc[j], s, 64);
    }
    if (lane == 0) {
        double logit[8];
#pragma unroll
        for (int e = 0; e < 8; e++) {
            double cl = acc[e] + (double)bg[e];
            double nl = acc[8 + e] + (double)bn[e];
            double sp = (nl > 30.0) ? nl : log1p(exp(nl));
            logit[e] = cl + (double)noise[(size_t)t * 8 + e] * sp;
        }
        int i1 = -1, i2 = -1;
        double v1 = -1e300, v2 = -1e300;
#pragma unroll
        for (int e = 0; e < 8; e++) {
            double v = logit[e];
            if (v > v1) { v2 = v1; i2 = i1; v1 = v; i1 = e; }
            else if (v > v2) { v2 = v; i2 = e; }
        }
        double d = exp(v2 - v1);
        tok_e[t] = make_int2(i1, i2);
        tok_w[t] = make_float2((float)(1.0 / (1.0 + d)), (float)(d / (1.0 + d)));
        atomicAdd(&meta[i1], 1);
        atomicAdd(&meta[i2], 1);
    }
}

__global__ void offsets_kernel(int* meta) {
    if (threadIdx.x == 0 && blockIdx.x == 0) {
        int off = 0;
        for (int e = 0; e < 8; e++) {
            meta[16 + e] = off;
            off += (meta[e] + PAD - 1) / PAD * PAD;
            meta[8 + e] = 0;  // cursor
        }
        meta[24] = off;  // padTotal
    }
}

// Wave-aggregated slot assignment (atomic order doesn't affect any FP result).
__global__ void assign_kernel(int* meta, const int2* tok_e, const float2* tok_w,
                              int2* tok_pos, int* rowtok, float* rowwt) {
    int t = blockIdx.x * 256 + threadIdx.x;
    int lane = threadIdx.x & 63;
    int2 e = tok_e[t];
    float2 wt = tok_w[t];
    int sel[2] = {e.x, e.y};
    float ww[2] = {wt.x, wt.y};
    int pos[2];
#pragma unroll
    for (int s = 0; s < 2; s++) {
        int p = 0;
#pragma unroll
        for (int ex = 0; ex < 8; ex++) {
            unsigned long long m = __ballot(sel[s] == ex);
            if (m) {
                int leader = __ffsll((unsigned long long)m) - 1;
                int base = 0;
                if (lane == leader) base = atomicAdd(&meta[8 + ex], (int)__popcll(m));
                base = __shfl(base, leader, 64);
                if (sel[s] == ex)
                    p = meta[16 + ex] + base + (int)__popcll(m & ((1ull << lane) - 1ull));
            }
        }
        pos[s] = p;
        rowtok[p] = t;
        rowwt[p] = ww[s];
    }
    tok_pos[t] = make_int2(pos[0], pos[1]);
}

// Gather token rows into packed order, fp32 -> bf16.
__global__ void gather_x_kernel(const float* __restrict__ x, const int* __restrict__ rowtok,
                                unsigned short* __restrict__ Xg) {
    int p = blockIdx.x;
    int tok = rowtok[p];
    const float4* src = (const float4*)(x + (size_t)tok * C_DIM);
    ushort4* dst = (ushort4*)(Xg + (size_t)p * C_DIM);
    int i = threadIdx.x;  // 256 threads x 4 elems = 1024
    float4 v = src[i];
    ushort4 o;
    o.x = f2bf(v.x); o.y = f2bf(v.y); o.z = f2bf(v.z); o.w = f2bf(v.w);
    dst[i] = o;
}

// [E][R][S] fp32 -> [E][S][R] bf16, 64x64 tiles, vectorized both sides.
__global__ __launch_bounds__(256) void transpose_bf16_kernel(
    const float* __restrict__ in, unsigned short* __restrict__ out, int R, int S) {
    __shared__ float tile[64][68];
    const float* ine = in + (size_t)blockIdx.z * R * S;
    unsigned short* oute = out + (size_t)blockIdx.z * R * S;
    int s0 = blockIdx.x * 64, r0 = blockIdx.y * 64;
    int tid = threadIdx.x;
    int rr = tid >> 2, cs = (tid & 3) * 16;
    const float4* src = (const float4*)(ine + (size_t)(r0 + rr) * S + s0 + cs);
#pragma unroll
    for (int q = 0; q < 4; q++) *(float4*)&tile[rr][cs + q * 4] = src[q];
    __syncthreads();
    int ss = tid >> 2, rs = (tid & 3) * 16;
    ushort4 o[4];
#pragma unroll
    for (int q = 0; q < 4; q++) {
        ushort4 v;
        v.x = f2bf(tile[rs + q * 4 + 0][ss]);
        v.y = f2bf(tile[rs + q * 4 + 1][ss]);
        v.z = f2bf(tile[rs + q * 4 + 2][ss]);
        v.w = f2bf(tile[rs + q * 4 + 3][ss]);
        o[q] = v;
    }
    ushort4* dst = (ushort4*)(oute + (size_t)(s0 + ss) * R + r0 + rs);
#pragma unroll
    for (int q = 0; q < 4; q++) dst[q] = o[q];
}

// ---------------------------------------------------------------------------
// GEMM1: 256x256 tile, 512 threads (8 waves = 2M x 4N), BK=32, 4-deep LDS
// pipeline (4 x 32KB buffers = 128KB dynamic), counted vmcnt, raw barriers.
// Out = bf16(relu(acc + bias)). A:[rows][KDIM] bf16, Bt:[E][NDIM][KDIM] bf16.
// LDS tile: A[256][32] + B[256][32] bf16, row=64B, 2-bit XOR swizzle
// (slot ^ ((r>>1)&3)) applied on gload SOURCE and ds_read addr (rule #21).
// ---------------------------------------------------------------------------
template <int KDIM, int NDIM>
__global__ __launch_bounds__(512) void gemm1_kernel(
    const unsigned short* __restrict__ A, const unsigned short* __restrict__ Bt,
    const float* __restrict__ bias, unsigned short* __restrict__ Out,
    const int* __restrict__ meta) {
    extern __shared__ char ldsraw[];  // 131072 bytes
    int rowBase = blockIdx.x * 256;
    if (rowBase >= meta[24]) return;
    int e = 0;
#pragma unroll
    for (int i = 1; i < 8; i++)
        if (rowBase >= meta[16 + i]) e = i;
    int colBase = blockIdx.y * 256;

    int tid = threadIdx.x;
    int wv = tid >> 6, lane = tid & 63;
    int wr = wv >> 2, wcol = wv & 3;  // 2 x 4 waves

    const unsigned short* Ab = A + (size_t)rowBase * KDIM;
    const unsigned short* Bb = Bt + (size_t)e * NDIM * KDIM + (size_t)colBase * KDIM;

    // Staging source decode (thread-constant): LDS byte b -> (row, phys slot),
    // source k-slot = phys ^ ((r>>1)&3)  (inverse swizzle on SOURCE).
    int b0 = tid * 16, b1 = 8192 + tid * 16;
    int r0 = b0 >> 6, sl0 = ((b0 >> 4) & 3) ^ ((r0 >> 1) & 3);
    int r1 = b1 >> 6, sl1 = ((b1 >> 4) & 3) ^ ((r1 >> 1) & 3);
    const unsigned short* a0 = Ab + (size_t)r0 * KDIM + sl0 * 8;
    const unsigned short* a1 = Ab + (size_t)r1 * KDIM + sl1 * 8;
    const unsigned short* g0 = Bb + (size_t)r0 * KDIM + sl0 * 8;
    const unsigned short* g1 = Bb + (size_t)r1 * KDIM + sl1 * 8;
    int ldsOff0 = wv * 1024, ldsOff1 = 8192 + wv * 1024;  // wave-uniform bases

#define STAGE(tt) {                                                        \
        int k0s = (tt) * 32;                                               \
        char* bA_ = ldsraw + (((tt) & 3) << 15);                           \
        char* bB_ = bA_ + 16384;                                           \
        gload_lds16(a0 + k0s, bA_ + ldsOff0);                              \
        gload_lds16(a1 + k0s, bA_ + ldsOff1);                              \
        gload_lds16(g0 + k0s, bB_ + ldsOff0);                              \
        gload_lds16(g1 + k0s, bB_ + ldsOff1);                              \
    }

    // Fragment read offsets (swizzled), constant across K-steps.
    int aoff[8], boff[4];
#pragma unroll
    for (int m = 0; m < 8; m++) {
        int r = wr * 128 + m * 16 + (lane & 15);
        aoff[m] = r * 64 + ((((lane >> 4) ^ ((r >> 1) & 3))) << 4);
    }
#pragma unroll
    for (int n = 0; n < 4; n++) {
        int rb = wcol * 64 + n * 16 + (lane & 15);
        boff[n] = rb * 64 + ((((lane >> 4) ^ ((rb >> 1) & 3))) << 4);
    }

    f32x4 acc[8][4];
#pragma unroll
    for (int m = 0; m < 8; m++)
#pragma unroll
        for (int n = 0; n < 4; n++) acc[m][n] = f32x4{0.f, 0.f, 0.f, 0.f};

    constexpr int T = KDIM / 32;
    STAGE(0); STAGE(1); STAGE(2);
    __builtin_amdgcn_sched_barrier(0);

    for (int t = 0; t < T; ++t) {
        if (t + 3 < T) STAGE(t + 3);
        __builtin_amdgcn_sched_barrier(0);
        if (t + 3 < T)      asm volatile("s_waitcnt vmcnt(12)" ::: "memory");
        else if (t + 2 < T) asm volatile("s_waitcnt vmcnt(8)" ::: "memory");
        else if (t + 1 < T) asm volatile("s_waitcnt vmcnt(4)" ::: "memory");
        else                asm volatile("s_waitcnt vmcnt(0)" ::: "memory");
        __builtin_amdgcn_sched_barrier(0);
        __builtin_amdgcn_s_barrier();
        __builtin_amdgcn_sched_barrier(0);

        const char* bA = ldsraw + ((t & 3) << 15);
        const char* bB = bA + 16384;
        short8 af[8], bv4[4];
#pragma unroll
        for (int m = 0; m < 8; m++) af[m] = *(const short8*)(bA + aoff[m]);
#pragma unroll
        for (int n = 0; n < 4; n++) bv4[n] = *(const short8*)(bB + boff[n]);
#pragma unroll
        for (int m = 0; m < 8; m++)
#pragma unroll
            for (int n = 0; n < 4; n++)
                acc[m][n] = __builtin_amdgcn_mfma_f32_16x16x32_bf16(af[m], bv4[n], acc[m][n], 0, 0, 0);

        __builtin_amdgcn_sched_barrier(0);
        __builtin_amdgcn_s_barrier();
        __builtin_amdgcn_sched_barrier(0);
    }
#undef STAGE

    // Epilogue: bias + relu -> bf16, repack via LDS, coalesced 16B stores.
    unsigned short* lds16 = (unsigned short*)ldsraw;  // 256x256 bf16 = 128KB
    float bv[4];
#pragma unroll
    for (int n = 0; n < 4; n++)
        bv[n] = bias[(size_t)e * NDIM + colBase + wcol * 64 + n * 16 + (lane & 15)];
#pragma unroll
    for (int m = 0; m < 8; m++) {
#pragma unroll
        for (int n = 0; n < 4; n++) {
#pragma unroll
            for (int j = 0; j < 4; j++) {
                float v = fmaxf(acc[m][n][j] + bv[n], 0.f);
                int rr = wr * 128 + m * 16 + (lane >> 4) * 4 + j;
                int cc = wcol * 64 + n * 16 + (lane & 15);
                lds16[rr * 256 + cc] = f2bf(v);
            }
        }
    }
    __syncthreads();
    {
        int row = tid >> 1, half = tid & 1;
        const short8* s = (const short8*)(lds16 + row * 256 + half * 128);
        short8* dst = (short8*)(Out + (size_t)(rowBase + row) * NDIM + colBase + half * 128);
#pragma unroll
        for (int i = 0; i < 16; i++) dst[i] = s[i];
    }
}

// GEMM2 (unchanged structure): 128x128 tile, 4 waves, BK=64 as two 32-halves.
// Out = fp32((acc + bias) * rowwt[row]), direct stores.
template <int KDIM, int NDIM>
__global__ __launch_bounds__(256) void gemm2_kernel(
    const unsigned short* __restrict__ A, const unsigned short* __restrict__ Bt,
    const float* __restrict__ bias, const float* __restrict__ rowwt,
    float* __restrict__ Out, const int* __restrict__ meta) {
    int rowBase = blockIdx.x * 128;
    int padTotal = meta[24];
    if (rowBase >= padTotal) return;
    int e = 0;
#pragma unroll
    for (int i = 1; i < 8; i++)
        if (rowBase >= meta[16 + i]) e = i;
    int colBase = blockIdx.y * 128;

    __shared__ unsigned short lds[16384];
    unsigned short* Al = lds;
    unsigned short* Bl = lds + 8192;

    int tid = threadIdx.x;
    int wv = tid >> 6, lane = tid & 63;
    int wr = wv >> 1, wc = wv & 1;

    const unsigned short* Ab = A + (size_t)rowBase * KDIM;
    const unsigned short* Bb = Bt + (size_t)e * NDIM * KDIM + (size_t)colBase * KDIM;

    f32x4 acc[4][4];
#pragma unroll
    for (int m = 0; m < 4; m++)
#pragma unroll
        for (int n = 0; n < 4; n++) acc[m][n] = f32x4{0.f, 0.f, 0.f, 0.f};

    int aoff[4], boff[4];
#pragma unroll
    for (int m = 0; m < 4; m++) {
        int r = wr * 64 + m * 16 + (lane & 15);
        aoff[m] = r * 64 + ((((lane >> 4) ^ ((r >> 1) & 3))) << 4);
        int rb = wc * 64 + m * 16 + (lane & 15);
        boff[m] = rb * 64 + ((((lane >> 4) ^ ((rb >> 1) & 3))) << 4);
    }

    const int kSteps = KDIM / 64;
    for (int ks = 0; ks < kSteps; ++ks) {
        int k0 = ks * 64;
#pragma unroll
        for (int i = 0; i < 4; i++) {
            int ob = i * 4096 + wv * 1024;
            int o = ob + lane * 16;
            int kk = o >> 13;
            int rem = o & 8191;
            int r = rem >> 6;
            int cp = (rem >> 4) & 3;
            int cc = cp ^ ((r >> 1) & 3);
            gload_lds16(Ab + (size_t)r * KDIM + (k0 + kk * 32 + cc * 8), (char*)Al + ob);
            gload_lds16(Bb + (size_t)r * KDIM + (k0 + kk * 32 + cc * 8), (char*)Bl + ob);
        }
        __syncthreads();
#pragma unroll
        for (int kk = 0; kk < 2; kk++) {
            short8 af[4], bfr[4];
#pragma unroll
            for (int m = 0; m < 4; m++)
                af[m] = *(const short8*)((const char*)Al + kk * 8192 + aoff[m]);
#pragma unroll
            for (int n = 0; n < 4; n++)
                bfr[n] = *(const short8*)((const char*)Bl + kk * 8192 + boff[n]);
#pragma unroll
            for (int m = 0; m < 4; m++)
#pragma unroll
                for (int n = 0; n < 4; n++)
                    acc[m][n] = __builtin_amdgcn_mfma_f32_16x16x32_bf16(af[m], bfr[n], acc[m][n], 0, 0, 0);
        }
        __syncthreads();
    }

    float bv[4];
#pragma unroll
    for (int n = 0; n < 4; n++)
        bv[n] = bias[(size_t)e * NDIM + colBase + wc * 64 + n * 16 + (lane & 15)];
#pragma unroll
    for (int m = 0; m < 4; m++) {
        float wt[4];
#pragma unroll
        for (int j = 0; j < 4; j++)
            wt[j] = rowwt[rowBase + wr * 64 + m * 16 + (lane >> 4) * 4 + j];
#pragma unroll
        for (int n = 0; n < 4; n++) {
#pragma unroll
            for (int j = 0; j < 4; j++) {
                float v = (acc[m][n][j] + bv[n]) * wt[j];
                int rr = wr * 64 + m * 16 + (lane >> 4) * 4 + j;
                int cc = wc * 64 + n * 16 + (lane & 15);
                Out[(size_t)(rowBase + rr) * NDIM + colBase + cc] = v;
            }
        }
    }
}

__global__ void combine_kernel(const float* __restrict__ contrib,
                               const int2* __restrict__ tok_pos, float* __restrict__ out) {
    int t = blockIdx.x;
    int2 p = tok_pos[t];
    const float4* c0 = (const float4*)(contrib + (size_t)p.x * C_DIM);
    const float4* c1 = (const float4*)(contrib + (size_t)p.y * C_DIM);
    float4* o = (float4*)(out + (size_t)t * C_DIM);
    int i = threadIdx.x;
    float4 a = c0[i], b = c1[i];
    float4 r;
    r.x = a.x + b.x; r.y = a.y + b.y; r.z = a.z + b.z; r.w = a.w + b.w;
    o[i] = r;
}

extern "C" void kernel_launch(void* const* d_in, const int* in_sizes, int n_in,
                              void* d_out, int out_size, void* d_ws, size_t ws_size,
                              hipStream_t stream) {
    (void)in_sizes; (void)n_in; (void)out_size; (void)ws_size;
    const float* x       = (const float*)d_in[0];
    const float* noise   = (const float*)d_in[1];
    const float* w_gate  = (const float*)d_in[2];
    const float* b_gate  = (const float*)d_in[3];
    const float* w_noise = (const float*)d_in[4];
    const float* b_noise = (const float*)d_in[5];
    const float* w1      = (const float*)d_in[6];
    const float* b1      = (const float*)d_in[7];
    const float* w2      = (const float*)d_in[8];
    const float* b2      = (const float*)d_in[9];
    float* out = (float*)d_out;

    char* w = (char*)d_ws;
    size_t off = 0;
    int* meta = (int*)(w + off); off += 256;
    int2* tok_e = (int2*)(w + off); off += (size_t)NTOK * 8;
    float2* tok_w = (float2*)(w + off); off += (size_t)NTOK * 8;
    int2* tok_pos = (int2*)(w + off); off += (size_t)NTOK * 8;
    int* rowtok = (int*)(w + off); off += (size_t)MAXROWS * 4;
    float* rowwt = (float*)(w + off); off += (size_t)MAXROWS * 4;
    unsigned short* Xg = (unsigned short*)(w + off); off += (size_t)MAXROWS * C_DIM * 2;
    unsigned short* H = (unsigned short*)(w + off); off += (size_t)MAXROWS * DFF_DIM * 2;
    unsigned short* w1b = (unsigned short*)(w + off); off += (size_t)E_NUM * DFF_DIM * C_DIM * 2;
    unsigned short* w2b = (unsigned short*)(w + off); off += (size_t)E_NUM * C_DIM * DFF_DIM * 2;
    float* contrib = (float*)(w + off); off += (size_t)MAXROWS * C_DIM * 4;

    init_kernel<<<(MAXROWS + 255) / 256, 256, 0, stream>>>(meta, rowtok, rowwt);
    router_kernel<<<NTOK / 4, 256, 0, stream>>>(x, noise, w_gate, b_gate, w_noise, b_noise,
                                                meta, tok_e, tok_w);
    offsets_kernel<<<1, 64, 0, stream>>>(meta);
    assign_kernel<<<NTOK / 256, 256, 0, stream>>>(meta, tok_e, tok_w, tok_pos, rowtok, rowwt);
    gather_x_kernel<<<MAXROWS, 256, 0, stream>>>(x, rowtok, Xg);
    transpose_bf16_kernel<<<dim3(DFF_DIM / 64, C_DIM / 64, E_NUM), 256, 0, stream>>>(w1, w1b, C_DIM, DFF_DIM);
    transpose_bf16_kernel<<<dim3(C_DIM / 64, DFF_DIM / 64, E_NUM), 256, 0, stream>>>(w2, w2b, DFF_DIM, C_DIM);

    hipFuncSetAttribute((const void*)gemm1_kernel<C_DIM, DFF_DIM>,
                        hipFuncAttributeMaxDynamicSharedMemorySize, 131072);
    gemm1_kernel<C_DIM, DFF_DIM><<<dim3(MAXROWS / 256, DFF_DIM / 256), 512, 131072, stream>>>(
        Xg, w1b, b1, H, meta);
    gemm2_kernel<DFF_DIM, C_DIM><<<dim3(MAXROWS / 128, C_DIM / 128), 256, 0, stream>>>(
        H, w2b, b2, rowwt, contrib, meta);
    combine_kernel<<<NTOK, 256, 0, stream>>>(contrib, tok_pos, out);
}

// Round 4
// 816.874 us; speedup vs baseline: 1.1860x; 1.1075x over previous
//
#include <hip/hip_runtime.h>
#include <hip/hip_bf16.h>
#include <cmath>

#define DEVFN __device__ __forceinline__

typedef __attribute__((ext_vector_type(8))) short short8;
typedef __attribute__((ext_vector_type(4))) float f32x4;

constexpr int C_DIM   = 1024;
constexpr int E_NUM   = 8;
constexpr int DFF_DIM = 4096;
constexpr int NTOK    = 8192;       // B*T
constexpr int PAD     = 256;        // expert segment alignment
constexpr int MAXROWS = NTOK * 2 + E_NUM * PAD;  // 18432

DEVFN unsigned short f2bf(float f) {
    __hip_bfloat16 h = __float2bfloat16(f);
    return __builtin_bit_cast(unsigned short, h);
}
DEVFN float bf2f(unsigned short u) {
    return __bfloat162float(__builtin_bit_cast(__hip_bfloat16, u));
}
DEVFN void gload_lds16(const void* g, void* lds) {
    __builtin_amdgcn_global_load_lds(
        (const __attribute__((address_space(1))) unsigned int*)g,
        (__attribute__((address_space(3))) unsigned int*)lds, 16, 0, 0);
}

// meta layout (ints): [0..7] counts, [8..15] cursor, [16..24] offs (offs[8]=padTotal)

__global__ void init_kernel(int* meta, int* rowtok) {
    int gid = blockIdx.x * 256 + threadIdx.x;
    if (gid < 64) meta[gid] = 0;
    if (gid < MAXROWS) rowtok[gid] = 0;
}

// One wave per token: fp64-accumulated gate/noise logits -> exact top-2 + weights.
__global__ void router_kernel(const float* __restrict__ x, const float* __restrict__ noise,
                              const float* __restrict__ wg, const float* __restrict__ bg,
                              const float* __restrict__ wn, const float* __restrict__ bn,
                              int* meta, int2* tok_e, float2* tok_w) {
    int wv = threadIdx.x >> 6, lane = threadIdx.x & 63;
    int t = blockIdx.x * 4 + wv;
    const float* xr = x + (size_t)t * C_DIM;
    double acc[16];
#pragma unroll
    for (int i = 0; i < 16; i++) acc[i] = 0.0;
    for (int i = 0; i < C_DIM / 64; i++) {
        int c = lane + i * 64;
        double xv = (double)xr[c];
        const float* g = wg + c * E_NUM;
        const float* nz = wn + c * E_NUM;
#pragma unroll
        for (int e = 0; e < 8; e++) {
            acc[e]     += xv * (double)g[e];
            acc[8 + e] += xv * (double)nz[e];
        }
    }
#pragma unroll
    for (int s = 32; s >= 1; s >>= 1) {
#pragma unroll
        for (int j = 0; j < 16; j++) acc[j] += __shfl_xor(acc[j], s, 64);
    }
    if (lane == 0) {
        double logit[8];
#pragma unroll
        for (int e = 0; e < 8; e++) {
            double cl = acc[e] + (double)bg[e];
            double nl = acc[8 + e] + (double)bn[e];
            double sp = (nl > 30.0) ? nl : log1p(exp(nl));
            logit[e] = cl + (double)noise[(size_t)t * 8 + e] * sp;
        }
        int i1 = -1, i2 = -1;
        double v1 = -1e300, v2 = -1e300;
#pragma unroll
        for (int e = 0; e < 8; e++) {
            double v = logit[e];
            if (v > v1) { v2 = v1; i2 = i1; v1 = v; i1 = e; }
            else if (v > v2) { v2 = v; i2 = e; }
        }
        double d = exp(v2 - v1);
        tok_e[t] = make_int2(i1, i2);
        tok_w[t] = make_float2((float)(1.0 / (1.0 + d)), (float)(d / (1.0 + d)));
        atomicAdd(&meta[i1], 1);
        atomicAdd(&meta[i2], 1);
    }
}

__global__ void offsets_kernel(int* meta) {
    if (threadIdx.x == 0 && blockIdx.x == 0) {
        int off = 0;
        for (int e = 0; e < 8; e++) {
            meta[16 + e] = off;
            off += (meta[e] + PAD - 1) / PAD * PAD;
            meta[8 + e] = 0;  // cursor
        }
        meta[24] = off;  // padTotal
    }
}

// Wave-aggregated slot assignment (atomic order doesn't affect any FP result).
__global__ void assign_kernel(int* meta, const int2* tok_e,
                              int2* tok_pos, int* rowtok) {
    int t = blockIdx.x * 256 + threadIdx.x;
    int lane = threadIdx.x & 63;
    int2 e = tok_e[t];
    int sel[2] = {e.x, e.y};
    int pos[2];
#pragma unroll
    for (int s = 0; s < 2; s++) {
        int p = 0;
#pragma unroll
        for (int ex = 0; ex < 8; ex++) {
            unsigned long long m = __ballot(sel[s] == ex);
            if (m) {
                int leader = __ffsll((unsigned long long)m) - 1;
                int base = 0;
                if (lane == leader) base = atomicAdd(&meta[8 + ex], (int)__popcll(m));
                base = __shfl(base, leader, 64);
                if (sel[s] == ex)
                    p = meta[16 + ex] + base + (int)__popcll(m & ((1ull << lane) - 1ull));
            }
        }
        pos[s] = p;
        rowtok[p] = t;
    }
    tok_pos[t] = make_int2(pos[0], pos[1]);
}

// Gather token rows into packed order, fp32 -> bf16.
__global__ void gather_x_kernel(const float* __restrict__ x, const int* __restrict__ rowtok,
                                unsigned short* __restrict__ Xg) {
    int p = blockIdx.x;
    int tok = rowtok[p];
    const float4* src = (const float4*)(x + (size_t)tok * C_DIM);
    ushort4* dst = (ushort4*)(Xg + (size_t)p * C_DIM);
    int i = threadIdx.x;  // 256 threads x 4 elems = 1024
    float4 v = src[i];
    ushort4 o;
    o.x = f2bf(v.x); o.y = f2bf(v.y); o.z = f2bf(v.z); o.w = f2bf(v.w);
    dst[i] = o;
}

// [E][R][S] fp32 -> [E][S][R] bf16, 64x64 tiles, vectorized both sides.
__global__ __launch_bounds__(256) void transpose_bf16_kernel(
    const float* __restrict__ in, unsigned short* __restrict__ out, int R, int S) {
    __shared__ float tile[64][68];
    const float* ine = in + (size_t)blockIdx.z * R * S;
    unsigned short* oute = out + (size_t)blockIdx.z * R * S;
    int s0 = blockIdx.x * 64, r0 = blockIdx.y * 64;
    int tid = threadIdx.x;
    int rr = tid >> 2, cs = (tid & 3) * 16;
    const float4* src = (const float4*)(ine + (size_t)(r0 + rr) * S + s0 + cs);
#pragma unroll
    for (int q = 0; q < 4; q++) *(float4*)&tile[rr][cs + q * 4] = src[q];
    __syncthreads();
    int ss = tid >> 2, rs = (tid & 3) * 16;
    ushort4 o[4];
#pragma unroll
    for (int q = 0; q < 4; q++) {
        ushort4 v;
        v.x = f2bf(tile[rs + q * 4 + 0][ss]);
        v.y = f2bf(tile[rs + q * 4 + 1][ss]);
        v.z = f2bf(tile[rs + q * 4 + 2][ss]);
        v.w = f2bf(tile[rs + q * 4 + 3][ss]);
        o[q] = v;
    }
    ushort4* dst = (ushort4*)(oute + (size_t)(s0 + ss) * R + r0 + rs);
#pragma unroll
    for (int q = 0; q < 4; q++) dst[q] = o[q];
}

// ---------------------------------------------------------------------------
// Unified pipelined GEMM: 256x256 tile, 512 threads (8 waves = 2M x 4N),
// BK=64, depth-2 double buffer (2 x 64KB LDS), counted vmcnt(8), raw barriers.
// LDS tile layout per buffer: A[256 rows][64 k] (32KB) then B[256][64] (32KB),
// row = 128B, 16B-slot s stored at physical slot s ^ (row&7) (3-bit XOR
// swizzle; applied on gload SOURCE and on ds_read addr -> conflict-free).
// Block mapping: bijective XCD-chunked remap of linear tile id (col-fastest
// within a row-panel group -> A-panel L2 reuse on the same XCD).
// MODE 1: OutH = bf16(relu(acc + bias))               (gemm1 -> H)
// MODE 2: OutC{z} = fp32(acc + (z==0)*bias)           (gemm2 split-K partial)
// ---------------------------------------------------------------------------
template <int KDIM, int KLEN, int NDIM, int MODE>
__global__ __launch_bounds__(512) void gemm_pipe_kernel(
    const unsigned short* __restrict__ A, const unsigned short* __restrict__ Bt,
    const float* __restrict__ bias, unsigned short* __restrict__ OutH,
    float* __restrict__ OutC0, float* __restrict__ OutC1,
    const int* __restrict__ meta) {
    extern __shared__ char ldsraw[];  // 131072 bytes

    // Bijective XCD remap (m204), then decode tile (row, col), col-fastest.
    int nwg = gridDim.x;
    int orig = blockIdx.x;
    int q = nwg >> 3, r8 = nwg & 7;
    int xcd = orig & 7, idx = orig >> 3;
    int wgid = (xcd < r8 ? xcd * (q + 1) : r8 * (q + 1) + (xcd - r8) * q) + idx;
    constexpr int NCT = NDIM / 256;
    int rowBase = (wgid / NCT) * 256;
    int colBase = (wgid % NCT) * 256;
    if (rowBase >= meta[24]) return;
    int e = 0;
#pragma unroll
    for (int i = 1; i < 8; i++)
        if (rowBase >= meta[16 + i]) e = i;
    int koff = blockIdx.z * KLEN;

    int tid = threadIdx.x;
    int wv = tid >> 6, lane = tid & 63;
    int wr = wv >> 2, wcol = wv & 3;  // 2M x 4N waves

    const unsigned short* Ab = A + (size_t)rowBase * KDIM + koff;
    const unsigned short* Bb = Bt + (size_t)e * NDIM * KDIM + (size_t)colBase * KDIM + koff;

    // Staging: chunk i covers rows [i*64, i*64+64); thread -> (row, slot).
    // LDS dest byte (linear) = tid*16 + i*8192 ; source slot = s ^ (row&7).
    const unsigned short* asrc[4];
    const unsigned short* bsrc[4];
    int ldsW[4];  // wave-uniform LDS base per chunk
#pragma unroll
    for (int i = 0; i < 4; i++) {
        int ri = (tid >> 3) + i * 64;
        int ss = (tid & 7) ^ (ri & 7);
        asrc[i] = Ab + (size_t)ri * KDIM + ss * 8;
        bsrc[i] = Bb + (size_t)ri * KDIM + ss * 8;
        ldsW[i] = i * 8192 + wv * 1024;
    }

    auto stage = [&](int tt) {
        char* dst = ldsraw + ((tt & 1) << 16);
        int kadd = tt * 64;
#pragma unroll
        for (int i = 0; i < 4; i++) {
            gload_lds16(asrc[i] + kadd, dst + ldsW[i]);
            gload_lds16(bsrc[i] + kadd, dst + 32768 + ldsW[i]);
        }
    };

    // Fragment read offsets: row r, k-half kk -> byte r*128 + phys*16,
    // phys = ((kk<<2)|(lane>>4)) ^ (r&7); note r&7 == lane&7 for all frags.
    int physk0 = ((lane >> 4)) ^ (lane & 7);
    int physk1 = (4 | (lane >> 4)) ^ (lane & 7);
    int arow[8], brow[4];
#pragma unroll
    for (int m = 0; m < 8; m++) arow[m] = wr * 128 + m * 16 + (lane & 15);
#pragma unroll
    for (int n = 0; n < 4; n++) brow[n] = wcol * 64 + n * 16 + (lane & 15);

    f32x4 acc[8][4];
#pragma unroll
    for (int m = 0; m < 8; m++)
#pragma unroll
        for (int n = 0; n < 4; n++) acc[m][n] = f32x4{0.f, 0.f, 0.f, 0.f};

    constexpr int T = KLEN / 64;
    stage(0);
    __builtin_amdgcn_sched_barrier(0);

    for (int t = 0; t < T; ++t) {
        if (t + 1 < T) stage(t + 1);
        __builtin_amdgcn_sched_barrier(0);
        if (t + 1 < T) asm volatile("s_waitcnt vmcnt(8)" ::: "memory");
        else           asm volatile("s_waitcnt vmcnt(0)" ::: "memory");
        __builtin_amdgcn_sched_barrier(0);
        __builtin_amdgcn_s_barrier();
        __builtin_amdgcn_sched_barrier(0);

        const char* buf = ldsraw + ((t & 1) << 16);
#pragma unroll
        for (int kk = 0; kk < 2; kk++) {
            int phys = kk ? physk1 : physk0;
            short8 af[8], bv4[4];
#pragma unroll
            for (int m = 0; m < 8; m++)
                af[m] = *(const short8*)(buf + (arow[m] << 7) + (phys << 4));
#pragma unroll
            for (int n = 0; n < 4; n++)
                bv4[n] = *(const short8*)(buf + 32768 + (brow[n] << 7) + (phys << 4));
            __builtin_amdgcn_s_setprio(1);
#pragma unroll
            for (int m = 0; m < 8; m++)
#pragma unroll
                for (int n = 0; n < 4; n++)
                    acc[m][n] = __builtin_amdgcn_mfma_f32_16x16x32_bf16(af[m], bv4[n], acc[m][n], 0, 0, 0);
            __builtin_amdgcn_s_setprio(0);
        }
        __builtin_amdgcn_sched_barrier(0);
        __builtin_amdgcn_s_barrier();
        __builtin_amdgcn_sched_barrier(0);
    }

    if constexpr (MODE == 1) {
        // bias + relu -> bf16, repack via LDS (exactly 128KB), 16B stores.
        unsigned short* lds16 = (unsigned short*)ldsraw;
        float bv[4];
#pragma unroll
        for (int n = 0; n < 4; n++)
            bv[n] = bias[(size_t)e * NDIM + colBase + wcol * 64 + n * 16 + (lane & 15)];
#pragma unroll
        for (int m = 0; m < 8; m++) {
#pragma unroll
            for (int n = 0; n < 4; n++) {
#pragma unroll
                for (int j = 0; j < 4; j++) {
                    float v = fmaxf(acc[m][n][j] + bv[n], 0.f);
                    int rr = wr * 128 + m * 16 + (lane >> 4) * 4 + j;
                    int cc = wcol * 64 + n * 16 + (lane & 15);
                    lds16[rr * 256 + cc] = f2bf(v);
                }
            }
        }
        __syncthreads();
        int row = tid >> 1, half = tid & 1;
        const short8* s = (const short8*)(lds16 + row * 256 + half * 128);
        short8* dst = (short8*)(OutH + (size_t)(rowBase + row) * NDIM + colBase + half * 128);
#pragma unroll
        for (int i = 0; i < 16; i++) dst[i] = s[i];
    } else {
        // fp32 partial, bias only in z==0; weights applied in combine.
        float* Of = (blockIdx.z == 0) ? OutC0 : OutC1;
        float bv[4];
#pragma unroll
        for (int n = 0; n < 4; n++)
            bv[n] = (blockIdx.z == 0)
                    ? bias[(size_t)e * NDIM + colBase + wcol * 64 + n * 16 + (lane & 15)]
                    : 0.f;
#pragma unroll
        for (int m = 0; m < 8; m++) {
#pragma unroll
            for (int n = 0; n < 4; n++) {
#pragma unroll
                for (int j = 0; j < 4; j++) {
                    int rr = wr * 128 + m * 16 + (lane >> 4) * 4 + j;
                    int cc = wcol * 64 + n * 16 + (lane & 15);
                    Of[(size_t)(rowBase + rr) * NDIM + colBase + cc] = acc[m][n][j] + bv[n];
                }
            }
        }
    }
}

// out[t] = w0*(c0[p0]+c1[p0]) + w1*(c0[p1]+c1[p1])  (fixed order, deterministic)
__global__ void combine_kernel(const float* __restrict__ c0, const float* __restrict__ c1,
                               const int2* __restrict__ tok_pos, const float2* __restrict__ tok_w,
                               float* __restrict__ out) {
    int t = blockIdx.x;
    int2 p = tok_pos[t];
    float2 w = tok_w[t];
    int i = threadIdx.x;
    float4 a0 = ((const float4*)(c0 + (size_t)p.x * C_DIM))[i];
    float4 a1 = ((const float4*)(c1 + (size_t)p.x * C_DIM))[i];
    float4 b0 = ((const float4*)(c0 + (size_t)p.y * C_DIM))[i];
    float4 b1 = ((const float4*)(c1 + (size_t)p.y * C_DIM))[i];
    float4 r;
    r.x = w.x * (a0.x + a1.x) + w.y * (b0.x + b1.x);
    r.y = w.x * (a0.y + a1.y) + w.y * (b0.y + b1.y);
    r.z = w.x * (a0.z + a1.z) + w.y * (b0.z + b1.z);
    r.w = w.x * (a0.w + a1.w) + w.y * (b0.w + b1.w);
    ((float4*)(out + (size_t)t * C_DIM))[i] = r;
}

extern "C" void kernel_launch(void* const* d_in, const int* in_sizes, int n_in,
                              void* d_out, int out_size, void* d_ws, size_t ws_size,
                              hipStream_t stream) {
    (void)in_sizes; (void)n_in; (void)out_size; (void)ws_size;
    const float* x       = (const float*)d_in[0];
    const float* noise   = (const float*)d_in[1];
    const float* w_gate  = (const float*)d_in[2];
    const float* b_gate  = (const float*)d_in[3];
    const float* w_noise = (const float*)d_in[4];
    const float* b_noise = (const float*)d_in[5];
    const float* w1      = (const float*)d_in[6];
    const float* b1      = (const float*)d_in[7];
    const float* w2      = (const float*)d_in[8];
    const float* b2      = (const float*)d_in[9];
    float* out = (float*)d_out;

    char* w = (char*)d_ws;
    size_t off = 0;
    int* meta = (int*)(w + off); off += 256;
    int2* tok_e = (int2*)(w + off); off += (size_t)NTOK * 8;
    float2* tok_w = (float2*)(w + off); off += (size_t)NTOK * 8;
    int2* tok_pos = (int2*)(w + off); off += (size_t)NTOK * 8;
    int* rowtok = (int*)(w + off); off += (size_t)MAXROWS * 4;
    unsigned short* H = (unsigned short*)(w + off); off += (size_t)MAXROWS * DFF_DIM * 2;
    unsigned short* w2b = (unsigned short*)(w + off); off += (size_t)E_NUM * C_DIM * DFF_DIM * 2;
    float* c0 = (float*)(w + off); off += (size_t)MAXROWS * C_DIM * 4;
    unsigned short* Xg = (unsigned short*)(w + off); off += (size_t)MAXROWS * C_DIM * 2;
    unsigned short* w1b = (unsigned short*)(w + off); off += (size_t)E_NUM * DFF_DIM * C_DIM * 2;
    // c1 aliases [Xg, Xg + 75.5MB): Xg/w1b are dead once gemm1 has run, and
    // both are fully rewritten by gather/transpose on every call (replay-safe).
    float* c1 = (float*)Xg;

    init_kernel<<<(MAXROWS + 255) / 256, 256, 0, stream>>>(meta, rowtok);
    router_kernel<<<NTOK / 4, 256, 0, stream>>>(x, noise, w_gate, b_gate, w_noise, b_noise,
                                                meta, tok_e, tok_w);
    offsets_kernel<<<1, 64, 0, stream>>>(meta);
    assign_kernel<<<NTOK / 256, 256, 0, stream>>>(meta, tok_e, tok_pos, rowtok);
    gather_x_kernel<<<MAXROWS, 256, 0, stream>>>(x, rowtok, Xg);
    transpose_bf16_kernel<<<dim3(DFF_DIM / 64, C_DIM / 64, E_NUM), 256, 0, stream>>>(w1, w1b, C_DIM, DFF_DIM);
    transpose_bf16_kernel<<<dim3(C_DIM / 64, DFF_DIM / 64, E_NUM), 256, 0, stream>>>(w2, w2b, DFF_DIM, C_DIM);

    hipFuncSetAttribute((const void*)gemm_pipe_kernel<C_DIM, C_DIM, DFF_DIM, 1>,
                        hipFuncAttributeMaxDynamicSharedMemorySize, 131072);
    gemm_pipe_kernel<C_DIM, C_DIM, DFF_DIM, 1>
        <<<dim3((MAXROWS / 256) * (DFF_DIM / 256), 1, 1), 512, 131072, stream>>>(
            Xg, w1b, b1, H, nullptr, nullptr, meta);

    hipFuncSetAttribute((const void*)gemm_pipe_kernel<DFF_DIM, DFF_DIM / 2, C_DIM, 2>,
                        hipFuncAttributeMaxDynamicSharedMemorySize, 131072);
    gemm_pipe_kernel<DFF_DIM, DFF_DIM / 2, C_DIM, 2>
        <<<dim3((MAXROWS / 256) * (C_DIM / 256), 1, 2), 512, 131072, stream>>>(
            H, w2b, b2, nullptr, c0, c1, meta);

    combine_kernel<<<NTOK, 256, 0, stream>>>(c0, c1, tok_pos, tok_w, out);
}

// Round 5
// 749.966 us; speedup vs baseline: 1.2918x; 1.0892x over previous
//
#include <hip/hip_runtime.h>
#include <hip/hip_bf16.h>
#include <cmath>

#define DEVFN __device__ __forceinline__

typedef __attribute__((ext_vector_type(8))) short short8;
typedef __attribute__((ext_vector_type(4))) float f32x4;

constexpr int C_DIM   = 1024;
constexpr int E_NUM   = 8;
constexpr int DFF_DIM = 4096;
constexpr int NTOK    = 8192;       // B*T
constexpr int PAD     = 256;        // expert segment alignment
constexpr int MAXROWS = NTOK * 2 + E_NUM * PAD;  // 18432

DEVFN unsigned short f2bf(float f) {
    __hip_bfloat16 h = __float2bfloat16(f);
    return __builtin_bit_cast(unsigned short, h);
}
DEVFN void gload_lds16(const void* g, void* lds) {
    __builtin_amdgcn_global_load_lds(
        (const __attribute__((address_space(1))) unsigned int*)g,
        (__attribute__((address_space(3))) unsigned int*)lds, 16, 0, 0);
}

// meta layout (ints): [0..7] counts, [8..15] cursor, [16..24] offs (offs[8]=padTotal)

__global__ void init_kernel(int* meta, int* rowtok) {
    int gid = blockIdx.x * 256 + threadIdx.x;
    if (gid < 64) meta[gid] = 0;
    if (gid < MAXROWS) rowtok[gid] = 0;
}

// One wave per token: fp64-accumulated gate/noise logits -> exact top-2 + weights.
__global__ void router_kernel(const float* __restrict__ x, const float* __restrict__ noise,
                              const float* __restrict__ wg, const float* __restrict__ bg,
                              const float* __restrict__ wn, const float* __restrict__ bn,
                              int* meta, int2* tok_e, float2* tok_w) {
    int wv = threadIdx.x >> 6, lane = threadIdx.x & 63;
    int t = blockIdx.x * 4 + wv;
    const float* xr = x + (size_t)t * C_DIM;
    double acc[16];
#pragma unroll
    for (int i = 0; i < 16; i++) acc[i] = 0.0;
    for (int i = 0; i < C_DIM / 64; i++) {
        int c = lane + i * 64;
        double xv = (double)xr[c];
        const float* g = wg + c * E_NUM;
        const float* nz = wn + c * E_NUM;
#pragma unroll
        for (int e = 0; e < 8; e++) {
            acc[e]     += xv * (double)g[e];
            acc[8 + e] += xv * (double)nz[e];
        }
    }
#pragma unroll
    for (int s = 32; s >= 1; s >>= 1) {
#pragma unroll
        for (int j = 0; j < 16; j++) acc[j] += __shfl_xor(acc[j], s, 64);
    }
    if (lane == 0) {
        double logit[8];
#pragma unroll
        for (int e = 0; e < 8; e++) {
            double cl = acc[e] + (double)bg[e];
            double nl = acc[8 + e] + (double)bn[e];
            double sp = (nl > 30.0) ? nl : log1p(exp(nl));
            logit[e] = cl + (double)noise[(size_t)t * 8 + e] * sp;
        }
        int i1 = -1, i2 = -1;
        double v1 = -1e300, v2 = -1e300;
#pragma unroll
        for (int e = 0; e < 8; e++) {
            double v = logit[e];
            if (v > v1) { v2 = v1; i2 = i1; v1 = v; i1 = e; }
            else if (v > v2) { v2 = v; i2 = e; }
        }
        double d = exp(v2 - v1);
        tok_e[t] = make_int2(i1, i2);
        tok_w[t] = make_float2((float)(1.0 / (1.0 + d)), (float)(d / (1.0 + d)));
        atomicAdd(&meta[i1], 1);
        atomicAdd(&meta[i2], 1);
    }
}

__global__ void offsets_kernel(int* meta) {
    if (threadIdx.x == 0 && blockIdx.x == 0) {
        int off = 0;
        for (int e = 0; e < 8; e++) {
            meta[16 + e] = off;
            off += (meta[e] + PAD - 1) / PAD * PAD;
            meta[8 + e] = 0;  // cursor
        }
        meta[24] = off;  // padTotal
    }
}

// Wave-aggregated slot assignment (atomic order doesn't affect any FP result).
__global__ void assign_kernel(int* meta, const int2* tok_e,
                              int2* tok_pos, int* rowtok) {
    int t = blockIdx.x * 256 + threadIdx.x;
    int lane = threadIdx.x & 63;
    int2 e = tok_e[t];
    int sel[2] = {e.x, e.y};
    int pos[2];
#pragma unroll
    for (int s = 0; s < 2; s++) {
        int p = 0;
#pragma unroll
        for (int ex = 0; ex < 8; ex++) {
            unsigned long long m = __ballot(sel[s] == ex);
            if (m) {
                int leader = __ffsll((unsigned long long)m) - 1;
                int base = 0;
                if (lane == leader) base = atomicAdd(&meta[8 + ex], (int)__popcll(m));
                base = __shfl(base, leader, 64);
                if (sel[s] == ex)
                    p = meta[16 + ex] + base + (int)__popcll(m & ((1ull << lane) - 1ull));
            }
        }
        pos[s] = p;
        rowtok[p] = t;
    }
    tok_pos[t] = make_int2(pos[0], pos[1]);
}

// Gather token rows into packed order, fp32 -> bf16.
__global__ void gather_x_kernel(const float* __restrict__ x, const int* __restrict__ rowtok,
                                unsigned short* __restrict__ Xg) {
    int p = blockIdx.x;
    int tok = rowtok[p];
    const float4* src = (const float4*)(x + (size_t)tok * C_DIM);
    ushort4* dst = (ushort4*)(Xg + (size_t)p * C_DIM);
    int i = threadIdx.x;  // 256 threads x 4 elems = 1024
    float4 v = src[i];
    ushort4 o;
    o.x = f2bf(v.x); o.y = f2bf(v.y); o.z = f2bf(v.z); o.w = f2bf(v.w);
    dst[i] = o;
}

// [E][R][S] fp32 -> [E][S][R] bf16, 64x64 tiles, vectorized both sides.
__global__ __launch_bounds__(256) void transpose_bf16_kernel(
    const float* __restrict__ in, unsigned short* __restrict__ out, int R, int S) {
    __shared__ float tile[64][68];
    const float* ine = in + (size_t)blockIdx.z * R * S;
    unsigned short* oute = out + (size_t)blockIdx.z * R * S;
    int s0 = blockIdx.x * 64, r0 = blockIdx.y * 64;
    int tid = threadIdx.x;
    int rr = tid >> 2, cs = (tid & 3) * 16;
    const float4* src = (const float4*)(ine + (size_t)(r0 + rr) * S + s0 + cs);
#pragma unroll
    for (int q = 0; q < 4; q++) *(float4*)&tile[rr][cs + q * 4] = src[q];
    __syncthreads();
    int ss = tid >> 2, rs = (tid & 3) * 16;
    ushort4 o[4];
#pragma unroll
    for (int q = 0; q < 4; q++) {
        ushort4 v;
        v.x = f2bf(tile[rs + q * 4 + 0][ss]);
        v.y = f2bf(tile[rs + q * 4 + 1][ss]);
        v.z = f2bf(tile[rs + q * 4 + 2][ss]);
        v.w = f2bf(tile[rs + q * 4 + 3][ss]);
        o[q] = v;
    }
    ushort4* dst = (ushort4*)(oute + (size_t)(s0 + ss) * R + r0 + rs);
#pragma unroll
    for (int q = 0; q < 4; q++) dst[q] = o[q];
}

// ---------------------------------------------------------------------------
// 8-phase 256x256 GEMM (T3+T4+T5), 512 thr = 8 waves (2M x 4N), BK=64,
// dbuf x2 (2 x 64KB). Per iteration: 2 K-tiles, 8 phases; each phase:
// {ds_read subtile; stage 1 half-tile (2 gload_lds); barrier; setprio(1);
//  16 MFMA; setprio(0); barrier}. Counted vmcnt(4) at phases 4 & 8 only
// (derived: 2 stages issued after the needed half); vmcnt(0) at last-iter p4.
// LDS half-tile [128 rows][64 k] bf16, 16B slot s stored at s^(row&7)
// (swizzle on gload SOURCE + ds_read addr; dest linear per rule #21).
// Stage stream: p1:Ah0(t+1) p2:Ah1(t+1) p3:Bh0(t+2) p4:Bh1(t+2)
//               p5:Ah0(t+2) p6:Ah1(t+2) p7:Bh0(t+3) p8:Bh1(t+3)
// (each stage lands >=1 barrier after its buffer-half's last ds_read).
// MODE 1: OutH = bf16(relu(acc+bias));  MODE 2: OutC{z} = fp32(acc+(z==0)*bias)
// ---------------------------------------------------------------------------
template <int KDIM, int KLEN, int NDIM, int MODE>
__global__ __launch_bounds__(512) void gemm8_kernel(
    const unsigned short* __restrict__ A, const unsigned short* __restrict__ Bt,
    const float* __restrict__ bias, unsigned short* __restrict__ OutH,
    float* __restrict__ OutC0, float* __restrict__ OutC1,
    const int* __restrict__ meta) {
    extern __shared__ char ldsraw[];  // 131072 bytes

    // Bijective XCD remap (m204); tile decode col-fastest for A-panel L2 reuse.
    int nwg = gridDim.x;
    int orig = blockIdx.x;
    int q = nwg >> 3, r8 = nwg & 7;
    int xcd = orig & 7, idx = orig >> 3;
    int wgid = (xcd < r8 ? xcd * (q + 1) : r8 * (q + 1) + (xcd - r8) * q) + idx;
    constexpr int NCT = NDIM / 256;
    int rowBase = (wgid / NCT) * 256;
    int colBase = (wgid % NCT) * 256;
    if (rowBase >= meta[24]) return;
    int e = 0;
#pragma unroll
    for (int i = 1; i < 8; i++)
        if (rowBase >= meta[16 + i]) e = i;
    int koff = blockIdx.z * KLEN;

    int tid = threadIdx.x;
    int wv = tid >> 6, lane = tid & 63;
    int wr = wv >> 2, wcol = wv & 3;  // 2M x 4N waves; wave output 128x64

    const unsigned short* Ab = A + (size_t)rowBase * KDIM + koff;
    const unsigned short* Bb = Bt + (size_t)e * NDIM * KDIM + (size_t)colBase * KDIM + koff;

    // Staging source decode: LDS byte o = j*8192 + tid*16 -> row o>>7,
    // phys slot (o>>4)&7, src slot = phys ^ (row&7). (row&7 same for j=0,1.)
    int rA = tid >> 3;
    int sSl = ((tid & 7) ^ (rA & 7)) * 8;
    const unsigned short* pA0 = Ab + (size_t)rA * KDIM + sSl;
    const unsigned short* pB0 = Bb + (size_t)rA * KDIM + sSl;

#define STAGEA(bufoff, half, t) { \
        char* d_ = ldsraw + (bufoff) + (half) * 16384 + wv * 1024; \
        const unsigned short* s_ = pA0 + (size_t)(half) * (128 * KDIM) + (size_t)(t) * 64; \
        gload_lds16(s_, d_); \
        gload_lds16(s_ + (size_t)64 * KDIM, d_ + 8192); }
#define STAGEB(bufoff, half, t) { \
        char* d_ = ldsraw + (bufoff) + 32768 + (half) * 16384 + wv * 1024; \
        const unsigned short* s_ = pB0 + (size_t)(half) * (128 * KDIM) + (size_t)(t) * 64; \
        gload_lds16(s_, d_); \
        gload_lds16(s_ + (size_t)64 * KDIM, d_ + 8192); }

    // Fragment read offsets (within the wave's half): phys = slot ^ (lane&7).
    int physd = (lane >> 4) ^ (lane & 7);          // kk=0 slot group
    int kdel = (physd & 4) ? -64 : 64;             // byte delta to kk=1
    int arowb[8], browb[4];
#pragma unroll
    for (int m = 0; m < 8; m++)
        arowb[m] = (m * 16 + (lane & 15)) * 128 + physd * 16;
#pragma unroll
    for (int n = 0; n < 4; n++)
        browb[n] = ((wcol & 1) * 64 + n * 16 + (lane & 15)) * 128 + physd * 16;
    const char* aH0 = ldsraw + wr * 16384;                       // buf0 A half
    const char* bH0 = ldsraw + 32768 + (wcol >> 1) * 16384;      // buf0 B half
    const char* aH1 = aH0 + 65536;
    const char* bH1 = bH0 + 65536;

    short8 af[4][2], bf[4][2];
    f32x4 acc[8][4];
#pragma unroll
    for (int m = 0; m < 8; m++)
#pragma unroll
        for (int n = 0; n < 4; n++) acc[m][n] = f32x4{0.f, 0.f, 0.f, 0.f};

#define LDA4(base, mb) \
    _Pragma("unroll") for (int mm = 0; mm < 4; mm++) { \
        af[mm][0] = *(const short8*)((base) + arowb[(mb) + mm]); \
        af[mm][1] = *(const short8*)((base) + arowb[(mb) + mm] + kdel); }
#define LDB2(base, nb) \
    _Pragma("unroll") for (int nn = 0; nn < 2; nn++) { \
        bf[(nb) + nn][0] = *(const short8*)((base) + browb[(nb) + nn]); \
        bf[(nb) + nn][1] = *(const short8*)((base) + browb[(nb) + nn] + kdel); }
#define QUAD(mb, nb) \
    __builtin_amdgcn_s_setprio(1); \
    _Pragma("unroll") for (int mm = 0; mm < 4; mm++) \
    _Pragma("unroll") for (int nn = 0; nn < 2; nn++) \
    _Pragma("unroll") for (int kk = 0; kk < 2; kk++) \
        acc[(mb) + mm][(nb) + nn] = __builtin_amdgcn_mfma_f32_16x16x32_bf16( \
            af[mm][kk], bf[(nb) + nn][kk], acc[(mb) + mm][(nb) + nn], 0, 0, 0); \
    __builtin_amdgcn_s_setprio(0);
#define SB() __builtin_amdgcn_sched_barrier(0)
#define BAR() { SB(); __builtin_amdgcn_s_barrier(); SB(); }

    constexpr int T = KLEN / 64;
    static_assert(T % 2 == 0, "T even");
    constexpr int ITERS = T / 2;

    // Prologue: tile0 all 4 halves + tile1 B halves (Ah(1) staged at p1/p2).
    STAGEB(0, 0, 0) STAGEB(0, 1, 0) STAGEA(0, 0, 0) STAGEA(0, 1, 0)
    STAGEB(65536, 0, 1) STAGEB(65536, 1, 1)
    SB(); asm volatile("s_waitcnt vmcnt(4)" ::: "memory"); SB();
    __builtin_amdgcn_s_barrier(); SB();

#pragma unroll 1
    for (int i = 0; i < ITERS; ++i) {
        int t0 = 2 * i;
        bool last = (i == ITERS - 1);
        // ---- K-tile t0 (buf0) ----
        // P1
        LDA4(aH0, 0) LDB2(bH0, 0)
        STAGEA(65536, 0, t0 + 1)
        BAR(); QUAD(0, 0) BAR();
        // P2
        LDB2(bH0, 2)
        STAGEA(65536, 1, t0 + 1)
        BAR(); QUAD(0, 2) BAR();
        // P3
        LDA4(aH0, 4)
        if (!last) STAGEB(0, 0, t0 + 2)
        BAR(); QUAD(4, 0) BAR();
        // P4
        if (!last) STAGEB(0, 1, t0 + 2)
        SB(); __builtin_amdgcn_s_barrier(); SB();
        QUAD(4, 2)
        SB();
        if (last) { asm volatile("s_waitcnt vmcnt(0)" ::: "memory"); }
        else      { asm volatile("s_waitcnt vmcnt(4)" ::: "memory"); }
        BAR();
        // ---- K-tile t0+1 (buf1) ----
        // P5
        LDA4(aH1, 0) LDB2(bH1, 0)
        if (!last) STAGEA(0, 0, t0 + 2)
        BAR(); QUAD(0, 0) BAR();
        // P6
        LDB2(bH1, 2)
        if (!last) STAGEA(0, 1, t0 + 2)
        BAR(); QUAD(0, 2) BAR();
        // P7
        LDA4(aH1, 4)
        if (!last) STAGEB(65536, 0, t0 + 3)
        BAR(); QUAD(4, 0) BAR();
        // P8
        if (!last) STAGEB(65536, 1, t0 + 3)
        SB(); __builtin_amdgcn_s_barrier(); SB();
        QUAD(4, 2)
        SB();
        if (!last) { asm volatile("s_waitcnt vmcnt(4)" ::: "memory"); }
        BAR();
    }
#undef STAGEA
#undef STAGEB
#undef LDA4
#undef LDB2
#undef QUAD

    // Epilogue.
    float bv[4];
#pragma unroll
    for (int n = 0; n < 4; n++)
        bv[n] = bias[(size_t)e * NDIM + colBase + wcol * 64 + n * 16 + (lane & 15)];

    if constexpr (MODE == 1) {
        // relu -> bf16, repack via LDS with rr-XOR swizzle, coalesced 16B stores.
        unsigned short* lds16 = (unsigned short*)ldsraw;
#pragma unroll
        for (int m = 0; m < 8; m++) {
#pragma unroll
            for (int n = 0; n < 4; n++) {
#pragma unroll
                for (int j = 0; j < 4; j++) {
                    float v = fmaxf(acc[m][n][j] + bv[n], 0.f);
                    int rr = wr * 128 + m * 16 + (lane >> 4) * 4 + j;
                    int cc = wcol * 64 + n * 16 + (lane & 15);
                    lds16[rr * 256 + (cc ^ ((rr & 7) << 4))] = f2bf(v);
                }
            }
        }
        __syncthreads();
        int row = tid >> 1, half = tid & 1;
        int xr = (row & 7) << 4;
#pragma unroll
        for (int i = 0; i < 16; i++) {
            int cs = half * 128 + i * 8;
            short8 val = *(const short8*)(lds16 + row * 256 + (cs ^ xr));
            *(short8*)(OutH + (size_t)(rowBase + row) * NDIM + colBase + cs) = val;
        }
    } else {
        float* Of = (blockIdx.z == 0) ? OutC0 : OutC1;
        if (blockIdx.z != 0) {
#pragma unroll
            for (int n = 0; n < 4; n++) bv[n] = 0.f;
        }
#pragma unroll
        for (int m = 0; m < 8; m++) {
#pragma unroll
            for (int n = 0; n < 4; n++) {
#pragma unroll
                for (int j = 0; j < 4; j++) {
                    int rr = wr * 128 + m * 16 + (lane >> 4) * 4 + j;
                    int cc = wcol * 64 + n * 16 + (lane & 15);
                    Of[(size_t)(rowBase + rr) * NDIM + colBase + cc] = acc[m][n][j] + bv[n];
                }
            }
        }
    }
}

// out[t] = w0*(c0[p0]+c1[p0]) + w1*(c0[p1]+c1[p1])  (fixed order, deterministic)
__global__ void combine_kernel(const float* __restrict__ c0, const float* __restrict__ c1,
                               const int2* __restrict__ tok_pos, const float2* __restrict__ tok_w,
                               float* __restrict__ out) {
    int t = blockIdx.x;
    int2 p = tok_pos[t];
    float2 w = tok_w[t];
    int i = threadIdx.x;
    float4 a0 = ((const float4*)(c0 + (size_t)p.x * C_DIM))[i];
    float4 a1 = ((const float4*)(c1 + (size_t)p.x * C_DIM))[i];
    float4 b0 = ((const float4*)(c0 + (size_t)p.y * C_DIM))[i];
    float4 b1 = ((const float4*)(c1 + (size_t)p.y * C_DIM))[i];
    float4 r;
    r.x = w.x * (a0.x + a1.x) + w.y * (b0.x + b1.x);
    r.y = w.x * (a0.y + a1.y) + w.y * (b0.y + b1.y);
    r.z = w.x * (a0.z + a1.z) + w.y * (b0.z + b1.z);
    r.w = w.x * (a0.w + a1.w) + w.y * (b0.w + b1.w);
    ((float4*)(out + (size_t)t * C_DIM))[i] = r;
}

extern "C" void kernel_launch(void* const* d_in, const int* in_sizes, int n_in,
                              void* d_out, int out_size, void* d_ws, size_t ws_size,
                              hipStream_t stream) {
    (void)in_sizes; (void)n_in; (void)out_size; (void)ws_size;
    const float* x       = (const float*)d_in[0];
    const float* noise   = (const float*)d_in[1];
    const float* w_gate  = (const float*)d_in[2];
    const float* b_gate  = (const float*)d_in[3];
    const float* w_noise = (const float*)d_in[4];
    const float* b_noise = (const float*)d_in[5];
    const float* w1      = (const float*)d_in[6];
    const float* b1      = (const float*)d_in[7];
    const float* w2      = (const float*)d_in[8];
    const float* b2      = (const float*)d_in[9];
    float* out = (float*)d_out;

    char* w = (char*)d_ws;
    size_t off = 0;
    int* meta = (int*)(w + off); off += 256;
    int2* tok_e = (int2*)(w + off); off += (size_t)NTOK * 8;
    float2* tok_w = (float2*)(w + off); off += (size_t)NTOK * 8;
    int2* tok_pos = (int2*)(w + off); off += (size_t)NTOK * 8;
    int* rowtok = (int*)(w + off); off += (size_t)MAXROWS * 4;
    unsigned short* H = (unsigned short*)(w + off); off += (size_t)MAXROWS * DFF_DIM * 2;
    unsigned short* w2b = (unsigned short*)(w + off); off += (size_t)E_NUM * C_DIM * DFF_DIM * 2;
    float* c0 = (float*)(w + off); off += (size_t)MAXROWS * C_DIM * 4;
    unsigned short* Xg = (unsigned short*)(w + off); off += (size_t)MAXROWS * C_DIM * 2;
    unsigned short* w1b = (unsigned short*)(w + off); off += (size_t)E_NUM * DFF_DIM * C_DIM * 2;
    // c1 aliases [Xg, Xg + 75.5MB): Xg/w1b are dead once gemm1 has run, and
    // both are fully rewritten by gather/transpose on every call (replay-safe).
    float* c1 = (float*)Xg;

    init_kernel<<<(MAXROWS + 255) / 256, 256, 0, stream>>>(meta, rowtok);
    router_kernel<<<NTOK / 4, 256, 0, stream>>>(x, noise, w_gate, b_gate, w_noise, b_noise,
                                                meta, tok_e, tok_w);
    offsets_kernel<<<1, 64, 0, stream>>>(meta);
    assign_kernel<<<NTOK / 256, 256, 0, stream>>>(meta, tok_e, tok_pos, rowtok);
    gather_x_kernel<<<MAXROWS, 256, 0, stream>>>(x, rowtok, Xg);
    transpose_bf16_kernel<<<dim3(DFF_DIM / 64, C_DIM / 64, E_NUM), 256, 0, stream>>>(w1, w1b, C_DIM, DFF_DIM);
    transpose_bf16_kernel<<<dim3(C_DIM / 64, DFF_DIM / 64, E_NUM), 256, 0, stream>>>(w2, w2b, DFF_DIM, C_DIM);

    hipFuncSetAttribute((const void*)gemm8_kernel<C_DIM, C_DIM, DFF_DIM, 1>,
                        hipFuncAttributeMaxDynamicSharedMemorySize, 131072);
    gemm8_kernel<C_DIM, C_DIM, DFF_DIM, 1>
        <<<dim3((MAXROWS / 256) * (DFF_DIM / 256), 1, 1), 512, 131072, stream>>>(
            Xg, w1b, b1, H, nullptr, nullptr, meta);

    hipFuncSetAttribute((const void*)gemm8_kernel<DFF_DIM, DFF_DIM / 2, C_DIM, 2>,
                        hipFuncAttributeMaxDynamicSharedMemorySize, 131072);
    gemm8_kernel<DFF_DIM, DFF_DIM / 2, C_DIM, 2>
        <<<dim3((MAXROWS / 256) * (C_DIM / 256), 1, 2), 512, 131072, stream>>>(
            H, w2b, b2, nullptr, c0, c1, meta);

    combine_kernel<<<NTOK, 256, 0, stream>>>(c0, c1, tok_pos, tok_w, out);
}

// Round 6
// 737.916 us; speedup vs baseline: 1.3129x; 1.0163x over previous
//
#include <hip/hip_runtime.h>
#include <hip/hip_bf16.h>
#include <cmath>

#define DEVFN __device__ __forceinline__

typedef __attribute__((ext_vector_type(8))) short short8;
typedef __attribute__((ext_vector_type(4))) float f32x4;

constexpr int C_DIM   = 1024;
constexpr int E_NUM   = 8;
constexpr int DFF_DIM = 4096;
constexpr int NTOK    = 8192;       // B*T
constexpr int PAD     = 256;        // expert segment alignment
constexpr int MAXROWS = NTOK * 2 + E_NUM * PAD;  // 18432

DEVFN unsigned short f2bf(float f) {
    __hip_bfloat16 h = __float2bfloat16(f);
    return __builtin_bit_cast(unsigned short, h);
}
DEVFN void gload_lds16(const void* g, void* lds) {
    __builtin_amdgcn_global_load_lds(
        (const __attribute__((address_space(1))) unsigned int*)g,
        (__attribute__((address_space(3))) unsigned int*)lds, 16, 0, 0);
}

// meta layout (ints): [0..7] counts, [8..15] cursor, [16..24] offs (offs[8]=padTotal)

__global__ void init_kernel(int* meta, int* rowtok) {
    int gid = blockIdx.x * 256 + threadIdx.x;
    if (gid < 64) meta[gid] = 0;
    if (gid < MAXROWS) rowtok[gid] = 0;
}

// One-time: wg[c][e], wn[c][e] -> wT[o][c] (o<8: gate, o>=8: noise). 16K elems.
__global__ void wrouter_T_kernel(const float* __restrict__ wg, const float* __restrict__ wn,
                                 float* __restrict__ wT) {
    int i = blockIdx.x * 256 + threadIdx.x;  // 16384
    int o = i >> 10, c = i & 1023;
    wT[i] = (o < 8) ? wg[c * 8 + o] : wn[c * 8 + (o - 8)];
}

// Router: 32 tokens/block, 8 threads/token. Coalesced x float4 loads,
// broadcast wT loads, fp64 accumulation (exact products, fp64 adds).
// 3-step shfl_xor reduce in 8-lane groups; softplus/top-2 on masked lanes.
__global__ __launch_bounds__(256) void router_kernel(
    const float* __restrict__ x, const float* __restrict__ noise,
    const float* __restrict__ wT, const float* __restrict__ bg,
    const float* __restrict__ bn, int* meta, int2* tok_e, float2* tok_w) {
    int tid = threadIdx.x;
    int tt = tid >> 3, sub = tid & 7;
    int tok = blockIdx.x * 32 + tt;
    const float* xr = x + (size_t)tok * C_DIM;

    double acc[16];
#pragma unroll
    for (int o = 0; o < 16; o++) acc[o] = 0.0;

#pragma unroll 4
    for (int i = 0; i < 32; i++) {
        int c = i * 32 + sub * 4;
        float4 xv = *(const float4*)(xr + c);
#pragma unroll
        for (int o = 0; o < 16; o++) {
            float4 wv = *(const float4*)(wT + o * C_DIM + c);
            acc[o] += (double)xv.x * (double)wv.x;
            acc[o] += (double)xv.y * (double)wv.y;
            acc[o] += (double)xv.z * (double)wv.z;
            acc[o] += (double)xv.w * (double)wv.w;
        }
    }
    // Reduce across the 8 sub-lanes (consecutive lanes within the wave).
#pragma unroll
    for (int s = 1; s <= 4; s <<= 1) {
#pragma unroll
        for (int o = 0; o < 16; o++) acc[o] += __shfl_xor(acc[o], s, 64);
    }
    if (sub == 0) {
        double logit[8];
#pragma unroll
        for (int e = 0; e < 8; e++) {
            double cl = acc[e] + (double)bg[e];
            double nl = acc[8 + e] + (double)bn[e];
            double sp = (nl > 30.0) ? nl : log1p(exp(nl));
            logit[e] = cl + (double)noise[(size_t)tok * 8 + e] * sp;
        }
        int i1 = -1, i2 = -1;
        double v1 = -1e300, v2 = -1e300;
#pragma unroll
        for (int e = 0; e < 8; e++) {
            double v = logit[e];
            if (v > v1) { v2 = v1; i2 = i1; v1 = v; i1 = e; }
            else if (v > v2) { v2 = v; i2 = e; }
        }
        double d = exp(v2 - v1);
        tok_e[tok] = make_int2(i1, i2);
        tok_w[tok] = make_float2((float)(1.0 / (1.0 + d)), (float)(d / (1.0 + d)));
        atomicAdd(&meta[i1], 1);
        atomicAdd(&meta[i2], 1);
    }
}

__global__ void offsets_kernel(int* meta) {
    if (threadIdx.x == 0 && blockIdx.x == 0) {
        int off = 0;
        for (int e = 0; e < 8; e++) {
            meta[16 + e] = off;
            off += (meta[e] + PAD - 1) / PAD * PAD;
            meta[8 + e] = 0;  // cursor
        }
        meta[24] = off;  // padTotal
    }
}

// Wave-aggregated slot assignment (atomic order doesn't affect any FP result).
__global__ void assign_kernel(int* meta, const int2* tok_e,
                              int2* tok_pos, int* rowtok) {
    int t = blockIdx.x * 256 + threadIdx.x;
    int lane = threadIdx.x & 63;
    int2 e = tok_e[t];
    int sel[2] = {e.x, e.y};
    int pos[2];
#pragma unroll
    for (int s = 0; s < 2; s++) {
        int p = 0;
#pragma unroll
        for (int ex = 0; ex < 8; ex++) {
            unsigned long long m = __ballot(sel[s] == ex);
            if (m) {
                int leader = __ffsll((unsigned long long)m) - 1;
                int base = 0;
                if (lane == leader) base = atomicAdd(&meta[8 + ex], (int)__popcll(m));
                base = __shfl(base, leader, 64);
                if (sel[s] == ex)
                    p = meta[16 + ex] + base + (int)__popcll(m & ((1ull << lane) - 1ull));
            }
        }
        pos[s] = p;
        rowtok[p] = t;
    }
    tok_pos[t] = make_int2(pos[0], pos[1]);
}

// Gather token rows into packed order, fp32 -> bf16.
__global__ void gather_x_kernel(const float* __restrict__ x, const int* __restrict__ rowtok,
                                unsigned short* __restrict__ Xg) {
    int p = blockIdx.x;
    int tok = rowtok[p];
    const float4* src = (const float4*)(x + (size_t)tok * C_DIM);
    ushort4* dst = (ushort4*)(Xg + (size_t)p * C_DIM);
    int i = threadIdx.x;  // 256 threads x 4 elems = 1024
    float4 v = src[i];
    ushort4 o;
    o.x = f2bf(v.x); o.y = f2bf(v.y); o.z = f2bf(v.z); o.w = f2bf(v.w);
    dst[i] = o;
}

// [E][R][S] fp32 -> [E][S][R] bf16, 64x64 tiles, vectorized both sides.
__global__ __launch_bounds__(256) void transpose_bf16_kernel(
    const float* __restrict__ in, unsigned short* __restrict__ out, int R, int S) {
    __shared__ float tile[64][68];
    const float* ine = in + (size_t)blockIdx.z * R * S;
    unsigned short* oute = out + (size_t)blockIdx.z * R * S;
    int s0 = blockIdx.x * 64, r0 = blockIdx.y * 64;
    int tid = threadIdx.x;
    int rr = tid >> 2, cs = (tid & 3) * 16;
    const float4* src = (const float4*)(ine + (size_t)(r0 + rr) * S + s0 + cs);
#pragma unroll
    for (int q = 0; q < 4; q++) *(float4*)&tile[rr][cs + q * 4] = src[q];
    __syncthreads();
    int ss = tid >> 2, rs = (tid & 3) * 16;
    ushort4 o[4];
#pragma unroll
    for (int q = 0; q < 4; q++) {
        ushort4 v;
        v.x = f2bf(tile[rs + q * 4 + 0][ss]);
        v.y = f2bf(tile[rs + q * 4 + 1][ss]);
        v.z = f2bf(tile[rs + q * 4 + 2][ss]);
        v.w = f2bf(tile[rs + q * 4 + 3][ss]);
        o[q] = v;
    }
    ushort4* dst = (ushort4*)(oute + (size_t)(s0 + ss) * R + r0 + rs);
#pragma unroll
    for (int q = 0; q < 4; q++) dst[q] = o[q];
}

// ---------------------------------------------------------------------------
// 8-phase 256x256 GEMM (T3+T4+T5), 512 thr = 8 waves (2M x 4N), BK=64,
// dbuf x2 (2 x 64KB). See R5 comments; unchanged this round.
// ---------------------------------------------------------------------------
template <int KDIM, int KLEN, int NDIM, int MODE>
__global__ __launch_bounds__(512) void gemm8_kernel(
    const unsigned short* __restrict__ A, const unsigned short* __restrict__ Bt,
    const float* __restrict__ bias, unsigned short* __restrict__ OutH,
    float* __restrict__ OutC0, float* __restrict__ OutC1,
    const int* __restrict__ meta) {
    extern __shared__ char ldsraw[];  // 131072 bytes

    // Bijective XCD remap (m204); tile decode col-fastest for A-panel L2 reuse.
    int nwg = gridDim.x;
    int orig = blockIdx.x;
    int q = nwg >> 3, r8 = nwg & 7;
    int xcd = orig & 7, idx = orig >> 3;
    int wgid = (xcd < r8 ? xcd * (q + 1) : r8 * (q + 1) + (xcd - r8) * q) + idx;
    constexpr int NCT = NDIM / 256;
    int rowBase = (wgid / NCT) * 256;
    int colBase = (wgid % NCT) * 256;
    if (rowBase >= meta[24]) return;
    int e = 0;
#pragma unroll
    for (int i = 1; i < 8; i++)
        if (rowBase >= meta[16 + i]) e = i;
    int koff = blockIdx.z * KLEN;

    int tid = threadIdx.x;
    int wv = tid >> 6, lane = tid & 63;
    int wr = wv >> 2, wcol = wv & 3;  // 2M x 4N waves; wave output 128x64

    const unsigned short* Ab = A + (size_t)rowBase * KDIM + koff;
    const unsigned short* Bb = Bt + (size_t)e * NDIM * KDIM + (size_t)colBase * KDIM + koff;

    int rA = tid >> 3;
    int sSl = ((tid & 7) ^ (rA & 7)) * 8;
    const unsigned short* pA0 = Ab + (size_t)rA * KDIM + sSl;
    const unsigned short* pB0 = Bb + (size_t)rA * KDIM + sSl;

#define STAGEA(bufoff, half, t) { \
        char* d_ = ldsraw + (bufoff) + (half) * 16384 + wv * 1024; \
        const unsigned short* s_ = pA0 + (size_t)(half) * (128 * KDIM) + (size_t)(t) * 64; \
        gload_lds16(s_, d_); \
        gload_lds16(s_ + (size_t)64 * KDIM, d_ + 8192); }
#define STAGEB(bufoff, half, t) { \
        char* d_ = ldsraw + (bufoff) + 32768 + (half) * 16384 + wv * 1024; \
        const unsigned short* s_ = pB0 + (size_t)(half) * (128 * KDIM) + (size_t)(t) * 64; \
        gload_lds16(s_, d_); \
        gload_lds16(s_ + (size_t)64 * KDIM, d_ + 8192); }

    int physd = (lane >> 4) ^ (lane & 7);          // kk=0 slot group
    int kdel = (physd & 4) ? -64 : 64;             // byte delta to kk=1
    int arowb[8], browb[4];
#pragma unroll
    for (int m = 0; m < 8; m++)
        arowb[m] = (m * 16 + (lane & 15)) * 128 + physd * 16;
#pragma unroll
    for (int n = 0; n < 4; n++)
        browb[n] = ((wcol & 1) * 64 + n * 16 + (lane & 15)) * 128 + physd * 16;
    const char* aH0 = ldsraw + wr * 16384;                       // buf0 A half
    const char* bH0 = ldsraw + 32768 + (wcol >> 1) * 16384;      // buf0 B half
    const char* aH1 = aH0 + 65536;
    const char* bH1 = bH0 + 65536;

    short8 af[4][2], bf[4][2];
    f32x4 acc[8][4];
#pragma unroll
    for (int m = 0; m < 8; m++)
#pragma unroll
        for (int n = 0; n < 4; n++) acc[m][n] = f32x4{0.f, 0.f, 0.f, 0.f};

#define LDA4(base, mb) \
    _Pragma("unroll") for (int mm = 0; mm < 4; mm++) { \
        af[mm][0] = *(const short8*)((base) + arowb[(mb) + mm]); \
        af[mm][1] = *(const short8*)((base) + arowb[(mb) + mm] + kdel); }
#define LDB2(base, nb) \
    _Pragma("unroll") for (int nn = 0; nn < 2; nn++) { \
        bf[(nb) + nn][0] = *(const short8*)((base) + browb[(nb) + nn]); \
        bf[(nb) + nn][1] = *(const short8*)((base) + browb[(nb) + nn] + kdel); }
#define QUAD(mb, nb) \
    __builtin_amdgcn_s_setprio(1); \
    _Pragma("unroll") for (int mm = 0; mm < 4; mm++) \
    _Pragma("unroll") for (int nn = 0; nn < 2; nn++) \
    _Pragma("unroll") for (int kk = 0; kk < 2; kk++) \
        acc[(mb) + mm][(nb) + nn] = __builtin_amdgcn_mfma_f32_16x16x32_bf16( \
            af[mm][kk], bf[(nb) + nn][kk], acc[(mb) + mm][(nb) + nn], 0, 0, 0); \
    __builtin_amdgcn_s_setprio(0);
#define SB() __builtin_amdgcn_sched_barrier(0)
#define BAR() { SB(); __builtin_amdgcn_s_barrier(); SB(); }

    constexpr int T = KLEN / 64;
    static_assert(T % 2 == 0, "T even");
    constexpr int ITERS = T / 2;

    // Prologue: tile0 all 4 halves + tile1 B halves (Ah(1) staged at p1/p2).
    STAGEB(0, 0, 0) STAGEB(0, 1, 0) STAGEA(0, 0, 0) STAGEA(0, 1, 0)
    STAGEB(65536, 0, 1) STAGEB(65536, 1, 1)
    SB(); asm volatile("s_waitcnt vmcnt(4)" ::: "memory"); SB();
    __builtin_amdgcn_s_barrier(); SB();

#pragma unroll 1
    for (int i = 0; i < ITERS; ++i) {
        int t0 = 2 * i;
        bool last = (i == ITERS - 1);
        // ---- K-tile t0 (buf0) ----
        LDA4(aH0, 0) LDB2(bH0, 0)
        STAGEA(65536, 0, t0 + 1)
        BAR(); QUAD(0, 0) BAR();
        LDB2(bH0, 2)
        STAGEA(65536, 1, t0 + 1)
        BAR(); QUAD(0, 2) BAR();
        LDA4(aH0, 4)
        if (!last) STAGEB(0, 0, t0 + 2)
        BAR(); QUAD(4, 0) BAR();
        if (!last) STAGEB(0, 1, t0 + 2)
        SB(); __builtin_amdgcn_s_barrier(); SB();
        QUAD(4, 2)
        SB();
        if (last) { asm volatile("s_waitcnt vmcnt(0)" ::: "memory"); }
        else      { asm volatile("s_waitcnt vmcnt(4)" ::: "memory"); }
        BAR();
        // ---- K-tile t0+1 (buf1) ----
        LDA4(aH1, 0) LDB2(bH1, 0)
        if (!last) STAGEA(0, 0, t0 + 2)
        BAR(); QUAD(0, 0) BAR();
        LDB2(bH1, 2)
        if (!last) STAGEA(0, 1, t0 + 2)
        BAR(); QUAD(0, 2) BAR();
        LDA4(aH1, 4)
        if (!last) STAGEB(65536, 0, t0 + 3)
        BAR(); QUAD(4, 0) BAR();
        if (!last) STAGEB(65536, 1, t0 + 3)
        SB(); __builtin_amdgcn_s_barrier(); SB();
        QUAD(4, 2)
        SB();
        if (!last) { asm volatile("s_waitcnt vmcnt(4)" ::: "memory"); }
        BAR();
    }
#undef STAGEA
#undef STAGEB
#undef LDA4
#undef LDB2
#undef QUAD

    // Epilogue.
    float bv[4];
#pragma unroll
    for (int n = 0; n < 4; n++)
        bv[n] = bias[(size_t)e * NDIM + colBase + wcol * 64 + n * 16 + (lane & 15)];

    if constexpr (MODE == 1) {
        // relu -> bf16, repack via LDS with rr-XOR swizzle, coalesced 16B stores.
        unsigned short* lds16 = (unsigned short*)ldsraw;
#pragma unroll
        for (int m = 0; m < 8; m++) {
#pragma unroll
            for (int n = 0; n < 4; n++) {
#pragma unroll
                for (int j = 0; j < 4; j++) {
                    float v = fmaxf(acc[m][n][j] + bv[n], 0.f);
                    int rr = wr * 128 + m * 16 + (lane >> 4) * 4 + j;
                    int cc = wcol * 64 + n * 16 + (lane & 15);
                    lds16[rr * 256 + (cc ^ ((rr & 7) << 4))] = f2bf(v);
                }
            }
        }
        __syncthreads();
        int row = tid >> 1, half = tid & 1;
        int xr = (row & 7) << 4;
#pragma unroll
        for (int i = 0; i < 16; i++) {
            int cs = half * 128 + i * 8;
            short8 val = *(const short8*)(lds16 + row * 256 + (cs ^ xr));
            *(short8*)(OutH + (size_t)(rowBase + row) * NDIM + colBase + cs) = val;
        }
    } else {
        float* Of = (blockIdx.z == 0) ? OutC0 : OutC1;
        if (blockIdx.z != 0) {
#pragma unroll
            for (int n = 0; n < 4; n++) bv[n] = 0.f;
        }
#pragma unroll
        for (int m = 0; m < 8; m++) {
#pragma unroll
            for (int n = 0; n < 4; n++) {
#pragma unroll
                for (int j = 0; j < 4; j++) {
                    int rr = wr * 128 + m * 16 + (lane >> 4) * 4 + j;
                    int cc = wcol * 64 + n * 16 + (lane & 15);
                    Of[(size_t)(rowBase + rr) * NDIM + colBase + cc] = acc[m][n][j] + bv[n];
                }
            }
        }
    }
}

// out[t] = w0*(c0[p0]+c1[p0]) + w1*(c0[p1]+c1[p1])  (fixed order, deterministic)
__global__ void combine_kernel(const float* __restrict__ c0, const float* __restrict__ c1,
                               const int2* __restrict__ tok_pos, const float2* __restrict__ tok_w,
                               float* __restrict__ out) {
    int t = blockIdx.x;
    int2 p = tok_pos[t];
    float2 w = tok_w[t];
    int i = threadIdx.x;
    float4 a0 = ((const float4*)(c0 + (size_t)p.x * C_DIM))[i];
    float4 a1 = ((const float4*)(c1 + (size_t)p.x * C_DIM))[i];
    float4 b0 = ((const float4*)(c0 + (size_t)p.y * C_DIM))[i];
    float4 b1 = ((const float4*)(c1 + (size_t)p.y * C_DIM))[i];
    float4 r;
    r.x = w.x * (a0.x + a1.x) + w.y * (b0.x + b1.x);
    r.y = w.x * (a0.y + a1.y) + w.y * (b0.y + b1.y);
    r.z = w.x * (a0.z + a1.z) + w.y * (b0.z + b1.z);
    r.w = w.x * (a0.w + a1.w) + w.y * (b0.w + b1.w);
    ((float4*)(out + (size_t)t * C_DIM))[i] = r;
}

extern "C" void kernel_launch(void* const* d_in, const int* in_sizes, int n_in,
                              void* d_out, int out_size, void* d_ws, size_t ws_size,
                              hipStream_t stream) {
    (void)in_sizes; (void)n_in; (void)out_size; (void)ws_size;
    const float* x       = (const float*)d_in[0];
    const float* noise   = (const float*)d_in[1];
    const float* w_gate  = (const float*)d_in[2];
    const float* b_gate  = (const float*)d_in[3];
    const float* w_noise = (const float*)d_in[4];
    const float* b_noise = (const float*)d_in[5];
    const float* w1      = (const float*)d_in[6];
    const float* b1      = (const float*)d_in[7];
    const float* w2      = (const float*)d_in[8];
    const float* b2      = (const float*)d_in[9];
    float* out = (float*)d_out;

    char* w = (char*)d_ws;
    size_t off = 0;
    int* meta = (int*)(w + off); off += 256;
    float* wT = (float*)(w + off); off += 16 * C_DIM * 4;
    int2* tok_e = (int2*)(w + off); off += (size_t)NTOK * 8;
    float2* tok_w = (float2*)(w + off); off += (size_t)NTOK * 8;
    int2* tok_pos = (int2*)(w + off); off += (size_t)NTOK * 8;
    int* rowtok = (int*)(w + off); off += (size_t)MAXROWS * 4;
    unsigned short* H = (unsigned short*)(w + off); off += (size_t)MAXROWS * DFF_DIM * 2;
    unsigned short* w2b = (unsigned short*)(w + off); off += (size_t)E_NUM * C_DIM * DFF_DIM * 2;
    float* c0 = (float*)(w + off); off += (size_t)MAXROWS * C_DIM * 4;
    unsigned short* Xg = (unsigned short*)(w + off); off += (size_t)MAXROWS * C_DIM * 2;
    unsigned short* w1b = (unsigned short*)(w + off); off += (size_t)E_NUM * DFF_DIM * C_DIM * 2;
    // c1 aliases [Xg, Xg + 75.5MB): Xg/w1b are dead once gemm1 has run, and
    // both are fully rewritten by gather/transpose on every call (replay-safe).
    float* c1 = (float*)Xg;

    init_kernel<<<(MAXROWS + 255) / 256, 256, 0, stream>>>(meta, rowtok);
    wrouter_T_kernel<<<64, 256, 0, stream>>>(w_gate, w_noise, wT);
    router_kernel<<<NTOK / 32, 256, 0, stream>>>(x, noise, wT, b_gate, b_noise,
                                                 meta, tok_e, tok_w);
    offsets_kernel<<<1, 64, 0, stream>>>(meta);
    assign_kernel<<<NTOK / 256, 256, 0, stream>>>(meta, tok_e, tok_pos, rowtok);
    gather_x_kernel<<<MAXROWS, 256, 0, stream>>>(x, rowtok, Xg);
    transpose_bf16_kernel<<<dim3(DFF_DIM / 64, C_DIM / 64, E_NUM), 256, 0, stream>>>(w1, w1b, C_DIM, DFF_DIM);
    transpose_bf16_kernel<<<dim3(C_DIM / 64, DFF_DIM / 64, E_NUM), 256, 0, stream>>>(w2, w2b, DFF_DIM, C_DIM);

    hipFuncSetAttribute((const void*)gemm8_kernel<C_DIM, C_DIM, DFF_DIM, 1>,
                        hipFuncAttributeMaxDynamicSharedMemorySize, 131072);
    gemm8_kernel<C_DIM, C_DIM, DFF_DIM, 1>
        <<<dim3((MAXROWS / 256) * (DFF_DIM / 256), 1, 1), 512, 131072, stream>>>(
            Xg, w1b, b1, H, nullptr, nullptr, meta);

    hipFuncSetAttribute((const void*)gemm8_kernel<DFF_DIM, DFF_DIM / 2, C_DIM, 2>,
                        hipFuncAttributeMaxDynamicSharedMemorySize, 131072);
    gemm8_kernel<DFF_DIM, DFF_DIM / 2, C_DIM, 2>
        <<<dim3((MAXROWS / 256) * (C_DIM / 256), 1, 2), 512, 131072, stream>>>(
            H, w2b, b2, nullptr, c0, c1, meta);

    combine_kernel<<<NTOK, 256, 0, stream>>>(c0, c1, tok_pos, tok_w, out);
}